// Round 5
// baseline (854.909 us; speedup 1.0000x reference)
//
#include <hip/hip_runtime.h>
#include <hip/hip_bf16.h>
#include <math.h>

typedef __hip_bfloat16 bf16;
typedef __attribute__((ext_vector_type(8))) short short8;
typedef __attribute__((ext_vector_type(4))) float f32x4;

#define C_DIM 384
#define SS 3
#define SCALE_ATTN 0.17677669529663687f  // 32^-0.5
#define LN_EPS 1e-5f

typedef const __attribute__((address_space(1))) void g_cvoid;
typedef __attribute__((address_space(3))) void l_void;
__device__ __forceinline__ void gl_lds16(const void* g, void* l) {
    __builtin_amdgcn_global_load_lds((g_cvoid*)g, (l_void*)l, 16, 0, 0);
}

// ---------------------------------------------------------------------------
// Weight transpose + fp32->bf16 cast: in fp32 [R][Cc] -> out bf16 [Cc][R]
// ---------------------------------------------------------------------------
__global__ void transpose_cast_kernel(const float* __restrict__ in, bf16* __restrict__ out,
                                      int R, int Cc) {
    int idx = blockIdx.x * 256 + threadIdx.x;
    if (idx < R * Cc) {
        int r = idx / Cc, c = idx - r * Cc;
        out[(size_t)c * R + r] = __float2bfloat16(in[idx]);
    }
}

// ---------------------------------------------------------------------------
// Fused bias table: BM[wi][h][64][64] fp32, padded; cols>=49 (or rows>=49)
// get -1e30 so attention needs no separate masking.
// ---------------------------------------------------------------------------
__global__ void build_bm_kernel(const float* __restrict__ rpb, const int* __restrict__ rel_idx,
                                const float* __restrict__ mask, float* __restrict__ BM) {
    int idx = blockIdx.x * 256 + threadIdx.x;   // < 64*12*4096
    int col = idx & 63, row = (idx >> 6) & 63;
    int h = (idx >> 12) % 12, wi = idx / (12 * 4096);
    float v = -1e30f;
    if (row < 49 && col < 49)
        v = rpb[rel_idx[row * 49 + col] * 12 + h] + mask[(size_t)wi * 2401 + row * 49 + col];
    BM[idx] = v;
}

// ---------------------------------------------------------------------------
// LN1 + cyclic shift + window partition.  One wave per output token.
// ---------------------------------------------------------------------------
__global__ __launch_bounds__(256)
void ln1_shift_window(const float* __restrict__ x, const float* __restrict__ g,
                      const float* __restrict__ bta, bf16* __restrict__ win) {
    int wave = threadIdx.x >> 6, lane = threadIdx.x & 63;
    int token = blockIdx.x * 4 + wave;
    int bw = token / 49, ntk = token - bw * 49;
    int bb = bw >> 6, wi = bw & 63;
    int wh = wi >> 3, wwi = wi & 7;
    int rr = ntk / 7, cc = ntk - rr * 7;
    int hs = wh * 7 + rr + SS; if (hs >= 56) hs -= 56;
    int ws = wwi * 7 + cc + SS; if (ws >= 56) ws -= 56;
    const float* src = x + ((size_t)(bb * 3136 + hs * 56 + ws)) * C_DIM;

    float v[6]; float s = 0.f, sq = 0.f;
    #pragma unroll
    for (int j = 0; j < 6; j++) {
        v[j] = src[lane + j * 64];
        s += v[j]; sq += v[j] * v[j];
    }
    #pragma unroll
    for (int o = 32; o > 0; o >>= 1) { s += __shfl_xor(s, o, 64); sq += __shfl_xor(sq, o, 64); }
    float mean = s * (1.0f / 384.0f);
    float var  = sq * (1.0f / 384.0f) - mean * mean;
    float rstd = rsqrtf(var + LN_EPS);

    bf16* dst = win + (size_t)token * C_DIM;
    #pragma unroll
    for (int j = 0; j < 6; j++) {
        int c = lane + j * 64;
        dst[c] = __float2bfloat16((v[j] - mean) * rstd * g[c] + bta[c]);
    }
}

// ---------------------------------------------------------------------------
// LN2 over fp32 xmid -> bf16
// ---------------------------------------------------------------------------
__global__ __launch_bounds__(256)
void ln2_kernel(const float* __restrict__ xmid, const float* __restrict__ g,
                const float* __restrict__ bta, bf16* __restrict__ out) {
    int wave = threadIdx.x >> 6, lane = threadIdx.x & 63;
    int token = blockIdx.x * 4 + wave;
    const float* src = xmid + (size_t)token * C_DIM;
    float v[6]; float s = 0.f, sq = 0.f;
    #pragma unroll
    for (int j = 0; j < 6; j++) {
        v[j] = src[lane + j * 64];
        s += v[j]; sq += v[j] * v[j];
    }
    #pragma unroll
    for (int o = 32; o > 0; o >>= 1) { s += __shfl_xor(s, o, 64); sq += __shfl_xor(sq, o, 64); }
    float mean = s * (1.0f / 384.0f);
    float var  = sq * (1.0f / 384.0f) - mean * mean;
    float rstd = rsqrtf(var + LN_EPS);
    bf16* dst = out + (size_t)token * C_DIM;
    #pragma unroll
    for (int j = 0; j < 6; j++) {
        int c = lane + j * 64;
        dst[c] = __float2bfloat16((v[j] - mean) * rstd * g[c] + bta[c]);
    }
}

// ---------------------------------------------------------------------------
// MFMA bf16 GEMM: BM=BN=128, BK=64, 4 waves 2x2, wave tile 64x64 (4x4 MFMA).
// Round-4 post-mortem: four schedules all hit the same ~200us wall set by
// bytes through the gl_lds->LDS->ds_read pipe (~16 B/cy/CU).  Fix: B (the
// WEIGHT, 0.3-1.2MB, L2/L1-resident) bypasses LDS entirely — fragments are
// loaded DIRECT from global into registers, prefetched one BK step ahead
// into named ping-pong sets (b0/b1, compile-time indexed).  This removes all
// B ds_writes + 8/wave/step B ds_reads (~55% of LDS-pipe work) and halves
// gl_lds traffic.  A keeps the proven gl_lds double-buffer; plain
// __syncthreads (no asm vmcnt — it would miscount compiler-tracked B loads).
// LDS 2x8KB=16KB.  1D grid, N-inner + bijective XCD chunk swizzle (A-strip
// re-reads stay XCD-local; weights replicate into every L2 - they're tiny).
// MODE 0: +bias -> bf16 ; 1: +bias+GELU -> bf16 ; 2: +bias+scatter+resid -> f32
// MODE 3: +bias+resid -> f32
// ---------------------------------------------------------------------------
template <int MODE>
__global__ __launch_bounds__(256)
void gemm_kernel(const bf16* __restrict__ A, const bf16* __restrict__ BT,
                 const float* __restrict__ bias, void* __restrict__ out,
                 const float* __restrict__ resid, int M, int N, int K) {
    __shared__ bf16 As[2][8192];   // 2 x 16KB  [panel(0..7)][row(0..127)][8]

    int tid = threadIdx.x;
    int wave = tid >> 6, lane = tid & 63, quad = lane >> 4, r = lane & 15;
    int wave_m = wave & 1, wave_n = wave >> 1;

    // --- 1D grid: bijective XCD chunk swizzle (8 XCDs), then N-inner decode ---
    int nN = N >> 7;
    int nwg = gridDim.x;
    int bid = blockIdx.x;
    int q8 = nwg >> 3, r8 = nwg & 7;
    int xcd = bid & 7, loc = bid >> 3;
    int swz = (xcd < r8 ? xcd * (q8 + 1) : r8 * (q8 + 1) + (xcd - r8) * q8) + loc;
    int mtile = swz / nN;
    int ntile = swz - mtile * nN;
    int m0 = mtile << 7, n0 = ntile << 7;

    // B fragment base: lane (quad,r) reads 16B at row (n0 + wn*64 + nt*16 + r)
    const bf16* Bp = BT + (size_t)(n0 + wave_n * 64 + r) * K + quad * 8;

    f32x4 acc[4][4] = {};
    short8 b0[4][2], b1[4][2];

    auto stage = [&](int buf, int k0) {
        #pragma unroll
        for (int c = 0; c < 4; c++) {
            int slot = c * 256 + wave * 64 + lane;   // 0..1023 = panel*128 + row
            int panel = slot >> 7, row = slot & 127;
            gl_lds16(A + (size_t)(m0 + row) * K + k0 + panel * 8,
                     &As[buf][(c * 256 + wave * 64) * 8]);
        }
    };

    #define LOADB(BS, k0)                                                       \
        _Pragma("unroll")                                                       \
        for (int nt = 0; nt < 4; nt++) {                                        \
            BS[nt][0] = *(const short8*)(Bp + (size_t)(nt * 16) * K + (k0));    \
            BS[nt][1] = *(const short8*)(Bp + (size_t)(nt * 16) * K + (k0) + 32); \
        }

    auto compute = [&](int buf, short8 (&b)[4][2]) {
        #pragma unroll
        for (int ks = 0; ks < 2; ks++) {
            int pq = ks * 4 + quad;
            short8 a[4];
            #pragma unroll
            for (int mt = 0; mt < 4; mt++)
                a[mt] = *(const short8*)&As[buf][(pq * 128 + wave_m * 64 + mt * 16 + r) * 8];
            __builtin_amdgcn_s_setprio(1);
            #pragma unroll
            for (int mt = 0; mt < 4; mt++)
                #pragma unroll
                for (int nt = 0; nt < 4; nt++)
                    acc[mt][nt] = __builtin_amdgcn_mfma_f32_16x16x32_bf16(
                        a[mt], b[nt][ks], acc[mt][nt], 0, 0, 0);
            __builtin_amdgcn_s_setprio(0);
        }
    };

    // prologue: A tile 0 staged, B frags 0 in regs
    stage(0, 0);
    LOADB(b0, 0)
    __syncthreads();

    int np = K >> 7;   // pairs of BK=64 steps; K in {384,1536} -> 3,12
    for (int p = 0; p < np; p++) {
        int k = p << 7;
        stage(1, k + 64); LOADB(b1, k + 64)      // prefetch next step
        compute(0, b0);                          // MFMA hides the prefetch
        __syncthreads();
        if (p + 1 < np) { stage(0, k + 128); LOADB(b0, k + 128) }
        compute(1, b1);
        __syncthreads();
    }
    #undef LOADB

    #pragma unroll
    for (int mt = 0; mt < 4; mt++) {
        #pragma unroll
        for (int nt = 0; nt < 4; nt++) {
            int n = n0 + wave_n * 64 + nt * 16 + r;
            float bv = bias[n];
            #pragma unroll
            for (int reg = 0; reg < 4; reg++) {
                int m = m0 + wave_m * 64 + mt * 16 + quad * 4 + reg;
                float v = acc[mt][nt][reg] + bv;
                if (MODE == 0) {
                    ((bf16*)out)[(size_t)m * N + n] = __float2bfloat16(v);
                } else if (MODE == 1) {
                    float gl = 0.5f * v * (1.0f + erff(v * 0.70710678118654752f));
                    ((bf16*)out)[(size_t)m * N + n] = __float2bfloat16(gl);
                } else if (MODE == 2) {
                    int bw = m / 49, ntk = m - bw * 49;
                    int bb = bw >> 6, wi = bw & 63;
                    int wh = wi >> 3, wwi = wi & 7;
                    int rr = ntk / 7, cc = ntk - rr * 7;
                    int ho = wh * 7 + rr + SS; if (ho >= 56) ho -= 56;
                    int wo = wwi * 7 + cc + SS; if (wo >= 56) wo -= 56;
                    size_t dst = ((size_t)(bb * 3136 + ho * 56 + wo)) * C_DIM + n;
                    ((float*)out)[dst] = v + resid[dst];
                } else {
                    size_t idx = (size_t)m * N + n;
                    ((float*)out)[idx] = v + resid[idx];
                }
            }
        }
    }
}

// ---------------------------------------------------------------------------
// MFMA windowed attention.  Wave-per-(window,head); grid (1024, 3), 4 waves.
// QK^T fragments direct from global; softmax in-register (C/D layout);
// P & V^T via XOR-swizzled wave-private LDS; PV via MFMA.  No barriers.
// Padded rows (>=49) clamp their source row to 0 — NEVER read OOB (the
// region past qkv holds the BM table whose bf16 reinterpretation is ~1e30,
// which overflowed S to inf/NaN in round 4).
// ---------------------------------------------------------------------------
__global__ __launch_bounds__(256)
void attn_mfma_kernel(const bf16* __restrict__ qkv, const float* __restrict__ BM,
                      bf16* __restrict__ out) {
    __shared__ bf16 P_lds[4][4096];   // [wave][64*64] swizzled
    __shared__ bf16 V_lds[4][2048];   // [wave][32*64] swizzled (V^T)
    int wave = threadIdx.x >> 6, lane = threadIdx.x & 63;
    int quad = lane >> 4, m16 = lane & 15;
    int bw = blockIdx.x;
    int h = blockIdx.y * 4 + wave;
    int wi = bw & 63;

    const bf16* base = qkv + (size_t)bw * 49 * 1152 + h * 32;

    // ---- stage V^T (d-major, swizzled); pad cols n>=49 with zeros ----
    bf16* Vt = V_lds[wave];
    #pragma unroll
    for (int it = 0; it < 16; it++) {
        int idx = it * 64 + lane;          // n*16 + dpair
        int n = idx >> 4, dp = idx & 15;
        int d0 = dp * 2;
        unsigned val = 0;
        if (n < 49)
            val = *(const unsigned*)(base + (size_t)n * 1152 + 768 + d0);
        bf16 v0 = ((const bf16*)&val)[0], v1 = ((const bf16*)&val)[1];
        int cb = (n & 56);                  // chunk<<3
        Vt[d0 * 64 + ((cb ^ ((d0 & 7) << 3)) | (n & 7))] = v0;
        int d1 = d0 + 1;
        Vt[d1 * 64 + ((cb ^ ((d1 & 7) << 3)) | (n & 7))] = v1;
    }

    // ---- QK^T: fragments direct from global (rows>=49 clamped to row 0) ----
    short8 qf[4], kf[4];
    #pragma unroll
    for (int t = 0; t < 4; t++) {
        int row = t * 16 + m16;
        int rc = (row < 49) ? row : 0;
        qf[t] = *(const short8*)(base + (size_t)rc * 1152 + quad * 8);
        kf[t] = *(const short8*)(base + (size_t)rc * 1152 + 384 + quad * 8);
    }
    f32x4 S[4][4] = {};
    #pragma unroll
    for (int mt = 0; mt < 4; mt++)
        #pragma unroll
        for (int nt = 0; nt < 4; nt++)
            S[mt][nt] = __builtin_amdgcn_mfma_f32_16x16x32_bf16(qf[mt], kf[nt], S[mt][nt], 0, 0, 0);

    // ---- scale + fused bias/mask + softmax (in C/D layout) ----
    const float* bmw = BM + (((size_t)wi * 12 + h) << 12);
    bf16* Pw = P_lds[wave];
    #pragma unroll
    for (int mt = 0; mt < 4; mt++) {
        #pragma unroll
        for (int reg = 0; reg < 4; reg++) {
            int row = mt * 16 + quad * 4 + reg;
            float p[4];
            float mx = -1e30f;
            #pragma unroll
            for (int nt = 0; nt < 4; nt++) {
                int col = nt * 16 + m16;
                float s = S[mt][nt][reg] * SCALE_ATTN + bmw[row * 64 + col];
                p[nt] = s;
                mx = fmaxf(mx, s);
            }
            #pragma unroll
            for (int o = 1; o < 16; o <<= 1) mx = fmaxf(mx, __shfl_xor(mx, o, 64));
            float sm = 0.f;
            #pragma unroll
            for (int nt = 0; nt < 4; nt++) { p[nt] = __expf(p[nt] - mx); sm += p[nt]; }
            #pragma unroll
            for (int o = 1; o < 16; o <<= 1) sm += __shfl_xor(sm, o, 64);
            float inv = 1.0f / sm;
            int r7 = (row & 7) << 3;
            #pragma unroll
            for (int nt = 0; nt < 4; nt++) {
                int col = nt * 16 + m16;
                int sw = ((col & 56) ^ r7) | (col & 7);
                Pw[row * 64 + sw] = __float2bfloat16(p[nt] * inv);
            }
        }
    }

    // ---- PV via MFMA (K=64 over padded n; pad cols of P are exactly 0) ----
    f32x4 O[4][2] = {};
    #pragma unroll
    for (int ks = 0; ks < 2; ks++) {
        int chunk = ks * 4 + quad;
        short8 pa[4], vb[2];
        #pragma unroll
        for (int mt = 0; mt < 4; mt++) {
            int row = mt * 16 + m16;
            pa[mt] = *(const short8*)&Pw[row * 64 + ((chunk ^ (row & 7)) << 3)];
        }
        #pragma unroll
        for (int nt = 0; nt < 2; nt++) {
            int d = nt * 16 + m16;
            vb[nt] = *(const short8*)&Vt[d * 64 + ((chunk ^ (d & 7)) << 3)];
        }
        #pragma unroll
        for (int mt = 0; mt < 4; mt++)
            #pragma unroll
            for (int nt = 0; nt < 2; nt++)
                O[mt][nt] = __builtin_amdgcn_mfma_f32_16x16x32_bf16(pa[mt], vb[nt], O[mt][nt], 0, 0, 0);
    }

    // ---- store [token][h*32+d], rows < 49 only ----
    bf16* orow = out + (size_t)bw * 49 * 384 + h * 32;
    #pragma unroll
    for (int mt = 0; mt < 4; mt++) {
        #pragma unroll
        for (int reg = 0; reg < 4; reg++) {
            int row = mt * 16 + quad * 4 + reg;
            if (row < 49) {
                #pragma unroll
                for (int nt = 0; nt < 2; nt++)
                    orow[(size_t)row * 384 + nt * 16 + m16] = __float2bfloat16(O[mt][nt][reg]);
            }
        }
    }
}

// ---------------------------------------------------------------------------
extern "C" void kernel_launch(void* const* d_in, const int* in_sizes, int n_in,
                              void* d_out, int out_size, void* d_ws, size_t ws_size,
                              hipStream_t stream) {
    const float* x      = (const float*)d_in[0];
    const float* g1     = (const float*)d_in[1];
    const float* b1     = (const float*)d_in[2];
    const float* qkv_w  = (const float*)d_in[3];
    const float* qkv_b  = (const float*)d_in[4];
    const float* rpb    = (const float*)d_in[5];
    const float* proj_w = (const float*)d_in[6];
    const float* proj_b = (const float*)d_in[7];
    const float* g2     = (const float*)d_in[8];
    const float* b2     = (const float*)d_in[9];
    const float* fc1_w  = (const float*)d_in[10];
    const float* fc1_b  = (const float*)d_in[11];
    const float* fc2_w  = (const float*)d_in[12];
    const float* fc2_b  = (const float*)d_in[13];
    const int*   rel_idx   = (const int*)d_in[14];
    const float* attn_mask = (const float*)d_in[15];

    const int M = 50176;  // 16 * 56 * 56 tokens = 1024 windows * 49

    char* ws = (char*)d_ws;
    size_t off = 0;
    bf16* bufA   = (bf16*)(ws + off); off += (size_t)M * 384 * 2;    // win / attn_out / ln2out
    bf16* bufBC  = (bf16*)(ws + off); off += (size_t)M * 1536 * 2;   // qkv (1152 cols) then h1 (1536)
    float* xmid  = (float*)(ws + off); off += (size_t)M * 384 * 4;   // residual mid, fp32
    bf16* qkv_wT  = (bf16*)(ws + off); off += (size_t)1152 * 384 * 2;
    bf16* proj_wT = (bf16*)(ws + off); off += (size_t)384 * 384 * 2;
    bf16* fc1_wT  = (bf16*)(ws + off); off += (size_t)1536 * 384 * 2;
    bf16* fc2_wT  = (bf16*)(ws + off); off += (size_t)384 * 1536 * 2;
    // BM table lives in the unused tail of bufBC (qkv uses only 1152 of 1536 cols)
    float* BM = (float*)(bufBC + (size_t)M * 1152);   // 64*12*64*64 f32 = 12.6MB < 38.5MB free

    build_bm_kernel<<<64 * 12 * 4096 / 256, 256, 0, stream>>>(rpb, rel_idx, attn_mask, BM);

    transpose_cast_kernel<<<(384 * 1152 + 255) / 256, 256, 0, stream>>>(qkv_w, qkv_wT, 384, 1152);
    transpose_cast_kernel<<<(384 * 384 + 255) / 256, 256, 0, stream>>>(proj_w, proj_wT, 384, 384);
    transpose_cast_kernel<<<(384 * 1536 + 255) / 256, 256, 0, stream>>>(fc1_w, fc1_wT, 384, 1536);
    transpose_cast_kernel<<<(1536 * 384 + 255) / 256, 256, 0, stream>>>(fc2_w, fc2_wT, 1536, 384);

    // LN1 + shift + window partition -> bf16 win
    ln1_shift_window<<<M / 4, 256, 0, stream>>>(x, g1, b1, bufA);

    // qkv = win @ qkv_w + b  -> bf16
    gemm_kernel<0><<<(M / 128) * (1152 / 128), 256, 0, stream>>>(
        bufA, qkv_wT, qkv_b, bufBC, nullptr, M, 1152, 384);

    // windowed attention (MFMA) -> bufA (bf16)
    attn_mfma_kernel<<<dim3(1024, 3), 256, 0, stream>>>(bufBC, BM, bufA);

    // proj + window reverse + unshift + residual x -> xmid (fp32)
    gemm_kernel<2><<<(M / 128) * (384 / 128), 256, 0, stream>>>(
        bufA, proj_wT, proj_b, xmid, x, M, 384, 384);

    // LN2 -> bufA (bf16)
    ln2_kernel<<<M / 4, 256, 0, stream>>>(xmid, g2, b2, bufA);

    // fc1 + GELU -> bufBC (bf16 h1)
    gemm_kernel<1><<<(M / 128) * (1536 / 128), 256, 0, stream>>>(
        bufA, fc1_wT, fc1_b, bufBC, nullptr, M, 1536, 384);

    // fc2 + residual xmid -> d_out (fp32)
    gemm_kernel<3><<<(M / 128) * (384 / 128), 256, 0, stream>>>(
        bufBC, fc2_wT, fc2_b, d_out, xmid, M, 384, 1536);
}

// Round 7
// 832.352 us; speedup vs baseline: 1.0271x; 1.0271x over previous
//
#include <hip/hip_runtime.h>
#include <hip/hip_bf16.h>
#include <math.h>

typedef __hip_bfloat16 bf16;
typedef __attribute__((ext_vector_type(8))) short short8;
typedef __attribute__((ext_vector_type(4))) float f32x4;

#define C_DIM 384
#define SS 3
#define SCALE_ATTN 0.17677669529663687f  // 32^-0.5
#define LN_EPS 1e-5f

typedef const __attribute__((address_space(1))) void g_cvoid;
typedef __attribute__((address_space(3))) void l_void;
__device__ __forceinline__ void gl_lds16(const void* g, void* l) {
    __builtin_amdgcn_global_load_lds((g_cvoid*)g, (l_void*)l, 16, 0, 0);
}

// ---------------------------------------------------------------------------
// Weight transpose + fp32->bf16 cast: in fp32 [R][Cc] -> out bf16 [Cc][R]
// ---------------------------------------------------------------------------
__global__ void transpose_cast_kernel(const float* __restrict__ in, bf16* __restrict__ out,
                                      int R, int Cc) {
    int idx = blockIdx.x * 256 + threadIdx.x;
    if (idx < R * Cc) {
        int r = idx / Cc, c = idx - r * Cc;
        out[(size_t)c * R + r] = __float2bfloat16(in[idx]);
    }
}

// ---------------------------------------------------------------------------
// Fused bias table: BM[wi][h][64][64] fp32, padded; cols>=49 (or rows>=49)
// get -1e30 so attention needs no separate masking.
// ---------------------------------------------------------------------------
__global__ void build_bm_kernel(const float* __restrict__ rpb, const int* __restrict__ rel_idx,
                                const float* __restrict__ mask, float* __restrict__ BM) {
    int idx = blockIdx.x * 256 + threadIdx.x;   // < 64*12*4096
    int col = idx & 63, row = (idx >> 6) & 63;
    int h = (idx >> 12) % 12, wi = idx / (12 * 4096);
    float v = -1e30f;
    if (row < 49 && col < 49)
        v = rpb[rel_idx[row * 49 + col] * 12 + h] + mask[(size_t)wi * 2401 + row * 49 + col];
    BM[idx] = v;
}

// ---------------------------------------------------------------------------
// LN1 + cyclic shift + window partition.  One wave per output token.
// ---------------------------------------------------------------------------
__global__ __launch_bounds__(256)
void ln1_shift_window(const float* __restrict__ x, const float* __restrict__ g,
                      const float* __restrict__ bta, bf16* __restrict__ win) {
    int wave = threadIdx.x >> 6, lane = threadIdx.x & 63;
    int token = blockIdx.x * 4 + wave;
    int bw = token / 49, ntk = token - bw * 49;
    int bb = bw >> 6, wi = bw & 63;
    int wh = wi >> 3, wwi = wi & 7;
    int rr = ntk / 7, cc = ntk - rr * 7;
    int hs = wh * 7 + rr + SS; if (hs >= 56) hs -= 56;
    int ws = wwi * 7 + cc + SS; if (ws >= 56) ws -= 56;
    const float* src = x + ((size_t)(bb * 3136 + hs * 56 + ws)) * C_DIM;

    float v[6]; float s = 0.f, sq = 0.f;
    #pragma unroll
    for (int j = 0; j < 6; j++) {
        v[j] = src[lane + j * 64];
        s += v[j]; sq += v[j] * v[j];
    }
    #pragma unroll
    for (int o = 32; o > 0; o >>= 1) { s += __shfl_xor(s, o, 64); sq += __shfl_xor(sq, o, 64); }
    float mean = s * (1.0f / 384.0f);
    float var  = sq * (1.0f / 384.0f) - mean * mean;
    float rstd = rsqrtf(var + LN_EPS);

    bf16* dst = win + (size_t)token * C_DIM;
    #pragma unroll
    for (int j = 0; j < 6; j++) {
        int c = lane + j * 64;
        dst[c] = __float2bfloat16((v[j] - mean) * rstd * g[c] + bta[c]);
    }
}

// ---------------------------------------------------------------------------
// LN2 over fp32 xmid -> bf16
// ---------------------------------------------------------------------------
__global__ __launch_bounds__(256)
void ln2_kernel(const float* __restrict__ xmid, const float* __restrict__ g,
                const float* __restrict__ bta, bf16* __restrict__ out) {
    int wave = threadIdx.x >> 6, lane = threadIdx.x & 63;
    int token = blockIdx.x * 4 + wave;
    const float* src = xmid + (size_t)token * C_DIM;
    float v[6]; float s = 0.f, sq = 0.f;
    #pragma unroll
    for (int j = 0; j < 6; j++) {
        v[j] = src[lane + j * 64];
        s += v[j]; sq += v[j] * v[j];
    }
    #pragma unroll
    for (int o = 32; o > 0; o >>= 1) { s += __shfl_xor(s, o, 64); sq += __shfl_xor(sq, o, 64); }
    float mean = s * (1.0f / 384.0f);
    float var  = sq * (1.0f / 384.0f) - mean * mean;
    float rstd = rsqrtf(var + LN_EPS);
    bf16* dst = out + (size_t)token * C_DIM;
    #pragma unroll
    for (int j = 0; j < 6; j++) {
        int c = lane + j * 64;
        dst[c] = __float2bfloat16((v[j] - mean) * rstd * g[c] + bta[c]);
    }
}

// ---------------------------------------------------------------------------
// MFMA bf16 GEMM (round-4 best): BM=256, BN=128, BK=32, 8 waves in 4x2 grid,
// wave tile 64x64.  T4 counted-vmcnt pipeline: 3 LDS buffers, depth-2
// prefetch, vmcnt(3) at the barrier.  Used for qkv and proj only.
// MODE 0: +bias -> bf16 ; 2: +bias+scatter+resid -> f32
// ---------------------------------------------------------------------------
template <int MODE>
__global__ __launch_bounds__(512)
void gemm_kernel(const bf16* __restrict__ A, const bf16* __restrict__ BT,
                 const float* __restrict__ bias, void* __restrict__ out,
                 const float* __restrict__ resid, int M, int N, int K) {
    __shared__ bf16 As[3][8192];   // 3 x 16KB  [panel(0..3)][row(0..255)][8]
    __shared__ bf16 Bs[3][4096];   // 3 x  8KB  [panel(0..3)][row(0..127)][8]

    int tid = threadIdx.x;
    int wave = tid >> 6, lane = tid & 63, quad = lane >> 4, r = lane & 15;
    int wave_m = wave >> 1, wave_n = wave & 1;   // 4 x 2

    int nN = N >> 7;
    int nwg = gridDim.x;
    int bid = blockIdx.x;
    int q8 = nwg >> 3, r8 = nwg & 7;
    int xcd = bid & 7, loc = bid >> 3;
    int swz = (xcd < r8 ? xcd * (q8 + 1) : r8 * (q8 + 1) + (xcd - r8) * q8) + loc;
    int mtile = swz / nN;
    int ntile = swz - mtile * nN;
    int m0 = mtile << 8, n0 = ntile << 7;

    f32x4 acc[4][4] = {};

    auto stage = [&](int buf, int k0) {
        #pragma unroll
        for (int c = 0; c < 2; c++) {
            int ai = wave * 2 + c;                 // 0..15
            int slot = ai * 64 + lane;             // 0..1023 = panel*256 + row
            int panel = slot >> 8, row = slot & 255;
            gl_lds16(A + (size_t)(m0 + row) * K + k0 + panel * 8,
                     &As[buf][(ai * 64) * 8]);
        }
        {
            int slot = wave * 64 + lane;           // 0..511 = panel*128 + row
            int panel = slot >> 7, row = slot & 127;
            gl_lds16(BT + (size_t)(n0 + row) * K + k0 + panel * 8,
                     &Bs[buf][(wave * 64) * 8]);
        }
    };

    auto compute = [&](int buf) {
        short8 a[4], b[4];
        #pragma unroll
        for (int mt = 0; mt < 4; mt++)
            a[mt] = *(const short8*)&As[buf][(quad * 256 + wave_m * 64 + mt * 16 + r) * 8];
        #pragma unroll
        for (int nt = 0; nt < 4; nt++)
            b[nt] = *(const short8*)&Bs[buf][(quad * 128 + wave_n * 64 + nt * 16 + r) * 8];
        __builtin_amdgcn_s_setprio(1);
        #pragma unroll
        for (int mt = 0; mt < 4; mt++)
            #pragma unroll
            for (int nt = 0; nt < 4; nt++)
                acc[mt][nt] = __builtin_amdgcn_mfma_f32_16x16x32_bf16(
                    a[mt], b[nt], acc[mt][nt], 0, 0, 0);
        __builtin_amdgcn_s_setprio(0);
    };

    int nk = K >> 5;

    stage(0, 0);
    stage(1, 32);
    asm volatile("s_waitcnt vmcnt(3)" ::: "memory");
    __builtin_amdgcn_s_barrier();
    __builtin_amdgcn_sched_barrier(0);

    int buf = 0;
    for (int kt = 0; kt < nk; kt++) {
        int pf = kt + 2;
        int pbuf = buf + 2; if (pbuf >= 3) pbuf -= 3;
        if (pf < nk) stage(pbuf, pf << 5);
        compute(buf);
        if (kt + 1 < nk) {
            __builtin_amdgcn_sched_barrier(0);
            if (pf < nk) asm volatile("s_waitcnt vmcnt(3)" ::: "memory");
            else         asm volatile("s_waitcnt vmcnt(0)" ::: "memory");
            __builtin_amdgcn_s_barrier();
            __builtin_amdgcn_sched_barrier(0);
        }
        buf++; if (buf == 3) buf = 0;
    }

    #pragma unroll
    for (int mt = 0; mt < 4; mt++) {
        #pragma unroll
        for (int nt = 0; nt < 4; nt++) {
            int n = n0 + wave_n * 64 + nt * 16 + r;
            float bv = bias[n];
            #pragma unroll
            for (int reg = 0; reg < 4; reg++) {
                int m = m0 + wave_m * 64 + mt * 16 + quad * 4 + reg;
                float v = acc[mt][nt][reg] + bv;
                if (MODE == 0) {
                    ((bf16*)out)[(size_t)m * N + n] = __float2bfloat16(v);
                } else if (MODE == 2) {
                    int bw = m / 49, ntk = m - bw * 49;
                    int bb = bw >> 6, wi = bw & 63;
                    int wh = wi >> 3, wwi = wi & 7;
                    int rr = ntk / 7, cc = ntk - rr * 7;
                    int ho = wh * 7 + rr + SS; if (ho >= 56) ho -= 56;
                    int wo = wwi * 7 + cc + SS; if (wo >= 56) wo -= 56;
                    size_t dst = ((size_t)(bb * 3136 + ho * 56 + wo)) * C_DIM + n;
                    ((float*)out)[dst] = v + resid[dst];
                }
            }
        }
    }
}

// ---------------------------------------------------------------------------
// FUSED MLP: out = xmid + fc2(gelu(fc1(ln2out))).  One block = 64-token strip.
// A (64x384) reg-staged once into XOR-swizzled LDS (FULL tile: 4 thr/token x
// 12 x 16B = 96 cols each — round-6 bug was j<6 covering only half).  Loop 12
// chunks of 128 hidden cols: phase1 h=A@W1 (W1 frags direct from global,
// L2-hot), GELU, write to double-buffered swizzled H_lds; barrier; phase2
// out-acc += h@W2 (W2 frags direct).  ONE barrier/chunk; h1 never touches
// HBM (was 154MB write + 154MB read); no per-step HBM drain on the critical
// path.  Swizzle: elem col' = col ^ ((row&7)<<3) (bits 3-5 only, bijective;
// short8 reads at 8-aligned col stay contiguous).
// Wave layout: phase1 4 waves over h-cols (wave tile 64x32, acc2[4][2]);
// phase2 4 waves over out-cols (wave tile 64x96, acc[4][6]).
// ---------------------------------------------------------------------------
__global__ __launch_bounds__(256)
void fused_mlp_kernel(const bf16* __restrict__ A, const bf16* __restrict__ W1T,
                      const float* __restrict__ fb1, const bf16* __restrict__ W2T,
                      const float* __restrict__ fb2, const float* __restrict__ resid,
                      float* __restrict__ out) {
    __shared__ bf16 A_lds[64 * 384];      // 48 KB, swizzled
    __shared__ bf16 H_lds[2][64 * 128];   // 2 x 16 KB, swizzled

    int tid = threadIdx.x;
    int wave = tid >> 6, lane = tid & 63, quad = lane >> 4, r = lane & 15;
    int m0 = blockIdx.x * 64;

    // ---- stage A: reg -> swizzled LDS (12 x 16B per thread = full 48KB) ----
    {
        int token = tid >> 2, part = tid & 3;     // 4 threads/token, 96 cols each
        const bf16* src = A + (size_t)(m0 + token) * 384 + part * 96;
        #pragma unroll
        for (int j = 0; j < 12; j++) {
            short8 v = *(const short8*)(src + j * 8);
            int col = part * 96 + j * 8;
            *(short8*)&A_lds[token * 384 + (col ^ ((token & 7) << 3))] = v;
        }
    }
    __syncthreads();

    f32x4 acc[4][6] = {};   // out acc: 64 tokens x 96 cols per wave

    int p = 0;
    for (int hc = 0; hc < 12; hc++) {
        // ---- phase 1: h_chunk[64 x 128] = A @ W1[:, hc*128 ...] ----
        f32x4 acc2[4][2] = {};
        #pragma unroll
        for (int ks = 0; ks < 12; ks++) {
            short8 a[4], b[2];
            #pragma unroll
            for (int mt = 0; mt < 4; mt++) {
                int row = mt * 16 + r;
                int col = ks * 32 + quad * 8;
                a[mt] = *(const short8*)&A_lds[row * 384 + (col ^ ((row & 7) << 3))];
            }
            #pragma unroll
            for (int nt = 0; nt < 2; nt++) {
                int n = hc * 128 + wave * 32 + nt * 16 + r;
                b[nt] = *(const short8*)(W1T + (size_t)n * 384 + ks * 32 + quad * 8);
            }
            #pragma unroll
            for (int mt = 0; mt < 4; mt++)
                #pragma unroll
                for (int nt = 0; nt < 2; nt++)
                    acc2[mt][nt] = __builtin_amdgcn_mfma_f32_16x16x32_bf16(
                        a[mt], b[nt], acc2[mt][nt], 0, 0, 0);
        }
        // bias + exact GELU -> swizzled H_lds (each wave writes its own cols)
        #pragma unroll
        for (int nt = 0; nt < 2; nt++) {
            int col = wave * 32 + nt * 16 + r;
            float bv = fb1[hc * 128 + col];
            #pragma unroll
            for (int mt = 0; mt < 4; mt++) {
                #pragma unroll
                for (int reg = 0; reg < 4; reg++) {
                    int row = mt * 16 + quad * 4 + reg;
                    float v = acc2[mt][nt][reg] + bv;
                    float gl = 0.5f * v * (1.0f + erff(v * 0.70710678118654752f));
                    H_lds[p][row * 128 + (col ^ ((row & 7) << 3))] = __float2bfloat16(gl);
                }
            }
        }
        __syncthreads();   // h_chunk complete (dbuf H: one barrier per chunk)

        // ---- phase 2: acc += h_chunk @ W2[hc*128 ... , :] ----
        #pragma unroll
        for (int ks = 0; ks < 4; ks++) {
            short8 a2[4], b2[6];
            #pragma unroll
            for (int mt = 0; mt < 4; mt++) {
                int row = mt * 16 + r;
                int col = ks * 32 + quad * 8;
                a2[mt] = *(const short8*)&H_lds[p][row * 128 + (col ^ ((row & 7) << 3))];
            }
            #pragma unroll
            for (int nt = 0; nt < 6; nt++) {
                int n = wave * 96 + nt * 16 + r;
                b2[nt] = *(const short8*)(W2T + (size_t)n * 1536 + hc * 128 + ks * 32 + quad * 8);
            }
            #pragma unroll
            for (int mt = 0; mt < 4; mt++)
                #pragma unroll
                for (int nt = 0; nt < 6; nt++)
                    acc[mt][nt] = __builtin_amdgcn_mfma_f32_16x16x32_bf16(
                        a2[mt], b2[nt], acc[mt][nt], 0, 0, 0);
        }
        p ^= 1;
    }

    // ---- epilogue: out = acc + fc2 bias + resid (f32) ----
    #pragma unroll
    for (int nt = 0; nt < 6; nt++) {
        int n = wave * 96 + nt * 16 + r;
        float bv = fb2[n];
        #pragma unroll
        for (int mt = 0; mt < 4; mt++) {
            #pragma unroll
            for (int reg = 0; reg < 4; reg++) {
                int m = m0 + mt * 16 + quad * 4 + reg;
                size_t idx = (size_t)m * 384 + n;
                out[idx] = acc[mt][nt][reg] + bv + resid[idx];
            }
        }
    }
}

// ---------------------------------------------------------------------------
// MFMA windowed attention.  Wave-per-(window,head); grid (1024, 3), 4 waves.
// ---------------------------------------------------------------------------
__global__ __launch_bounds__(256)
void attn_mfma_kernel(const bf16* __restrict__ qkv, const float* __restrict__ BM,
                      bf16* __restrict__ out) {
    __shared__ bf16 P_lds[4][4096];   // [wave][64*64] swizzled
    __shared__ bf16 V_lds[4][2048];   // [wave][32*64] swizzled (V^T)
    int wave = threadIdx.x >> 6, lane = threadIdx.x & 63;
    int quad = lane >> 4, m16 = lane & 15;
    int bw = blockIdx.x;
    int h = blockIdx.y * 4 + wave;
    int wi = bw & 63;

    const bf16* base = qkv + (size_t)bw * 49 * 1152 + h * 32;

    bf16* Vt = V_lds[wave];
    #pragma unroll
    for (int it = 0; it < 16; it++) {
        int idx = it * 64 + lane;          // n*16 + dpair
        int n = idx >> 4, dp = idx & 15;
        int d0 = dp * 2;
        unsigned val = 0;
        if (n < 49)
            val = *(const unsigned*)(base + (size_t)n * 1152 + 768 + d0);
        bf16 v0 = ((const bf16*)&val)[0], v1 = ((const bf16*)&val)[1];
        int cb = (n & 56);                  // chunk<<3
        Vt[d0 * 64 + ((cb ^ ((d0 & 7) << 3)) | (n & 7))] = v0;
        int d1 = d0 + 1;
        Vt[d1 * 64 + ((cb ^ ((d1 & 7) << 3)) | (n & 7))] = v1;
    }

    short8 qf[4], kf[4];
    #pragma unroll
    for (int t = 0; t < 4; t++) {
        int row = t * 16 + m16;
        int rc = (row < 49) ? row : 0;
        qf[t] = *(const short8*)(base + (size_t)rc * 1152 + quad * 8);
        kf[t] = *(const short8*)(base + (size_t)rc * 1152 + 384 + quad * 8);
    }
    f32x4 S[4][4] = {};
    #pragma unroll
    for (int mt = 0; mt < 4; mt++)
        #pragma unroll
        for (int nt = 0; nt < 4; nt++)
            S[mt][nt] = __builtin_amdgcn_mfma_f32_16x16x32_bf16(qf[mt], kf[nt], S[mt][nt], 0, 0, 0);

    const float* bmw = BM + (((size_t)wi * 12 + h) << 12);
    bf16* Pw = P_lds[wave];
    #pragma unroll
    for (int mt = 0; mt < 4; mt++) {
        #pragma unroll
        for (int reg = 0; reg < 4; reg++) {
            int row = mt * 16 + quad * 4 + reg;
            float p[4];
            float mx = -1e30f;
            #pragma unroll
            for (int nt = 0; nt < 4; nt++) {
                int col = nt * 16 + m16;
                float s = S[mt][nt][reg] * SCALE_ATTN + bmw[row * 64 + col];
                p[nt] = s;
                mx = fmaxf(mx, s);
            }
            #pragma unroll
            for (int o = 1; o < 16; o <<= 1) mx = fmaxf(mx, __shfl_xor(mx, o, 64));
            float sm = 0.f;
            #pragma unroll
            for (int nt = 0; nt < 4; nt++) { p[nt] = __expf(p[nt] - mx); sm += p[nt]; }
            #pragma unroll
            for (int o = 1; o < 16; o <<= 1) sm += __shfl_xor(sm, o, 64);
            float inv = 1.0f / sm;
            int r7 = (row & 7) << 3;
            #pragma unroll
            for (int nt = 0; nt < 4; nt++) {
                int col = nt * 16 + m16;
                int sw = ((col & 56) ^ r7) | (col & 7);
                Pw[row * 64 + sw] = __float2bfloat16(p[nt] * inv);
            }
        }
    }

    f32x4 O[4][2] = {};
    #pragma unroll
    for (int ks = 0; ks < 2; ks++) {
        int chunk = ks * 4 + quad;
        short8 pa[4], vb[2];
        #pragma unroll
        for (int mt = 0; mt < 4; mt++) {
            int row = mt * 16 + m16;
            pa[mt] = *(const short8*)&Pw[row * 64 + ((chunk ^ (row & 7)) << 3)];
        }
        #pragma unroll
        for (int nt = 0; nt < 2; nt++) {
            int d = nt * 16 + m16;
            vb[nt] = *(const short8*)&Vt[d * 64 + ((chunk ^ (d & 7)) << 3)];
        }
        #pragma unroll
        for (int mt = 0; mt < 4; mt++)
            #pragma unroll
            for (int nt = 0; nt < 2; nt++)
                O[mt][nt] = __builtin_amdgcn_mfma_f32_16x16x32_bf16(pa[mt], vb[nt], O[mt][nt], 0, 0, 0);
    }

    bf16* orow = out + (size_t)bw * 49 * 384 + h * 32;
    #pragma unroll
    for (int mt = 0; mt < 4; mt++) {
        #pragma unroll
        for (int reg = 0; reg < 4; reg++) {
            int row = mt * 16 + quad * 4 + reg;
            if (row < 49) {
                #pragma unroll
                for (int nt = 0; nt < 2; nt++)
                    orow[(size_t)row * 384 + nt * 16 + m16] = __float2bfloat16(O[mt][nt][reg]);
            }
        }
    }
}

// ---------------------------------------------------------------------------
extern "C" void kernel_launch(void* const* d_in, const int* in_sizes, int n_in,
                              void* d_out, int out_size, void* d_ws, size_t ws_size,
                              hipStream_t stream) {
    const float* x      = (const float*)d_in[0];
    const float* g1     = (const float*)d_in[1];
    const float* b1     = (const float*)d_in[2];
    const float* qkv_w  = (const float*)d_in[3];
    const float* qkv_b  = (const float*)d_in[4];
    const float* rpb    = (const float*)d_in[5];
    const float* proj_w = (const float*)d_in[6];
    const float* proj_b = (const float*)d_in[7];
    const float* g2     = (const float*)d_in[8];
    const float* b2     = (const float*)d_in[9];
    const float* fc1_w  = (const float*)d_in[10];
    const float* fc1_b  = (const float*)d_in[11];
    const float* fc2_w  = (const float*)d_in[12];
    const float* fc2_b  = (const float*)d_in[13];
    const int*   rel_idx   = (const int*)d_in[14];
    const float* attn_mask = (const float*)d_in[15];

    const int M = 50176;  // 16 * 56 * 56 tokens = 1024 windows * 49

    char* ws = (char*)d_ws;
    size_t off = 0;
    bf16* bufA   = (bf16*)(ws + off); off += (size_t)M * 384 * 2;    // win / attn_out / ln2out
    bf16* bufBC  = (bf16*)(ws + off); off += (size_t)M * 1536 * 2;   // qkv (1152 cols)
    float* xmid  = (float*)(ws + off); off += (size_t)M * 384 * 4;   // residual mid, fp32
    bf16* qkv_wT  = (bf16*)(ws + off); off += (size_t)1152 * 384 * 2;
    bf16* proj_wT = (bf16*)(ws + off); off += (size_t)384 * 384 * 2;
    bf16* fc1_wT  = (bf16*)(ws + off); off += (size_t)1536 * 384 * 2;
    bf16* fc2_wT  = (bf16*)(ws + off); off += (size_t)384 * 1536 * 2;
    // BM table lives in the unused tail of bufBC (qkv uses only 1152 of 1536 cols)
    float* BM = (float*)(bufBC + (size_t)M * 1152);   // 64*12*64*64 f32 = 12.6MB < 38.5MB free

    build_bm_kernel<<<64 * 12 * 4096 / 256, 256, 0, stream>>>(rpb, rel_idx, attn_mask, BM);

    transpose_cast_kernel<<<(384 * 1152 + 255) / 256, 256, 0, stream>>>(qkv_w, qkv_wT, 384, 1152);
    transpose_cast_kernel<<<(384 * 384 + 255) / 256, 256, 0, stream>>>(proj_w, proj_wT, 384, 384);
    transpose_cast_kernel<<<(384 * 1536 + 255) / 256, 256, 0, stream>>>(fc1_w, fc1_wT, 384, 1536);
    transpose_cast_kernel<<<(1536 * 384 + 255) / 256, 256, 0, stream>>>(fc2_w, fc2_wT, 1536, 384);

    // LN1 + shift + window partition -> bf16 win
    ln1_shift_window<<<M / 4, 256, 0, stream>>>(x, g1, b1, bufA);

    // qkv = win @ qkv_w + b  -> bf16
    gemm_kernel<0><<<(M / 256) * (1152 / 128), 512, 0, stream>>>(
        bufA, qkv_wT, qkv_b, bufBC, nullptr, M, 1152, 384);

    // windowed attention (MFMA) -> bufA (bf16)
    attn_mfma_kernel<<<dim3(1024, 3), 256, 0, stream>>>(bufBC, BM, bufA);

    // proj + window reverse + unshift + residual x -> xmid (fp32)
    gemm_kernel<2><<<(M / 256) * (384 / 128), 512, 0, stream>>>(
        bufA, proj_wT, proj_b, xmid, x, M, 384, 384);

    // LN2 -> bufA (bf16)
    ln2_kernel<<<M / 4, 256, 0, stream>>>(xmid, g2, b2, bufA);

    // fused MLP: d_out = xmid + fc2(gelu(fc1(bufA)))
    fused_mlp_kernel<<<M / 64, 256, 0, stream>>>(
        bufA, fc1_wT, fc1_b, fc2_wT, fc2_b, xmid, (float*)d_out);
}

// Round 8
// 716.837 us; speedup vs baseline: 1.1926x; 1.1611x over previous
//
#include <hip/hip_runtime.h>
#include <hip/hip_bf16.h>
#include <math.h>

typedef __hip_bfloat16 bf16;
typedef __attribute__((ext_vector_type(8))) short short8;
typedef __attribute__((ext_vector_type(4))) float f32x4;

#define C_DIM 384
#define SS 3
#define SCALE_ATTN 0.17677669529663687f  // 32^-0.5
#define LN_EPS 1e-5f

typedef const __attribute__((address_space(1))) void g_cvoid;
typedef __attribute__((address_space(3))) void l_void;
__device__ __forceinline__ void gl_lds16(const void* g, void* l) {
    __builtin_amdgcn_global_load_lds((g_cvoid*)g, (l_void*)l, 16, 0, 0);
}

// ---------------------------------------------------------------------------
// Weight transpose + fp32->bf16 cast: in fp32 [R][Cc] -> out bf16 [Cc][R]
// ---------------------------------------------------------------------------
__global__ void transpose_cast_kernel(const float* __restrict__ in, bf16* __restrict__ out,
                                      int R, int Cc) {
    int idx = blockIdx.x * 256 + threadIdx.x;
    if (idx < R * Cc) {
        int r = idx / Cc, c = idx - r * Cc;
        out[(size_t)c * R + r] = __float2bfloat16(in[idx]);
    }
}

// ---------------------------------------------------------------------------
// Fused bias table: BM[wi][h][64][64] fp32, padded; cols>=49 (or rows>=49)
// get -1e30 so attention needs no separate masking.
// ---------------------------------------------------------------------------
__global__ void build_bm_kernel(const float* __restrict__ rpb, const int* __restrict__ rel_idx,
                                const float* __restrict__ mask, float* __restrict__ BM) {
    int idx = blockIdx.x * 256 + threadIdx.x;   // < 64*12*4096
    int col = idx & 63, row = (idx >> 6) & 63;
    int h = (idx >> 12) % 12, wi = idx / (12 * 4096);
    float v = -1e30f;
    if (row < 49 && col < 49)
        v = rpb[rel_idx[row * 49 + col] * 12 + h] + mask[(size_t)wi * 2401 + row * 49 + col];
    BM[idx] = v;
}

// ---------------------------------------------------------------------------
// LN1 + cyclic shift + window partition.  One wave per output token.
// ---------------------------------------------------------------------------
__global__ __launch_bounds__(256)
void ln1_shift_window(const float* __restrict__ x, const float* __restrict__ g,
                      const float* __restrict__ bta, bf16* __restrict__ win) {
    int wave = threadIdx.x >> 6, lane = threadIdx.x & 63;
    int token = blockIdx.x * 4 + wave;
    int bw = token / 49, ntk = token - bw * 49;
    int bb = bw >> 6, wi = bw & 63;
    int wh = wi >> 3, wwi = wi & 7;
    int rr = ntk / 7, cc = ntk - rr * 7;
    int hs = wh * 7 + rr + SS; if (hs >= 56) hs -= 56;
    int ws = wwi * 7 + cc + SS; if (ws >= 56) ws -= 56;
    const float* src = x + ((size_t)(bb * 3136 + hs * 56 + ws)) * C_DIM;

    float v[6]; float s = 0.f, sq = 0.f;
    #pragma unroll
    for (int j = 0; j < 6; j++) {
        v[j] = src[lane + j * 64];
        s += v[j]; sq += v[j] * v[j];
    }
    #pragma unroll
    for (int o = 32; o > 0; o >>= 1) { s += __shfl_xor(s, o, 64); sq += __shfl_xor(sq, o, 64); }
    float mean = s * (1.0f / 384.0f);
    float var  = sq * (1.0f / 384.0f) - mean * mean;
    float rstd = rsqrtf(var + LN_EPS);

    bf16* dst = win + (size_t)token * C_DIM;
    #pragma unroll
    for (int j = 0; j < 6; j++) {
        int c = lane + j * 64;
        dst[c] = __float2bfloat16((v[j] - mean) * rstd * g[c] + bta[c]);
    }
}

// ---------------------------------------------------------------------------
// LN2 over fp32 xmid -> bf16
// ---------------------------------------------------------------------------
__global__ __launch_bounds__(256)
void ln2_kernel(const float* __restrict__ xmid, const float* __restrict__ g,
                const float* __restrict__ bta, bf16* __restrict__ out) {
    int wave = threadIdx.x >> 6, lane = threadIdx.x & 63;
    int token = blockIdx.x * 4 + wave;
    const float* src = xmid + (size_t)token * C_DIM;
    float v[6]; float s = 0.f, sq = 0.f;
    #pragma unroll
    for (int j = 0; j < 6; j++) {
        v[j] = src[lane + j * 64];
        s += v[j]; sq += v[j] * v[j];
    }
    #pragma unroll
    for (int o = 32; o > 0; o >>= 1) { s += __shfl_xor(s, o, 64); sq += __shfl_xor(sq, o, 64); }
    float mean = s * (1.0f / 384.0f);
    float var  = sq * (1.0f / 384.0f) - mean * mean;
    float rstd = rsqrtf(var + LN_EPS);
    bf16* dst = out + (size_t)token * C_DIM;
    #pragma unroll
    for (int j = 0; j < 6; j++) {
        int c = lane + j * 64;
        dst[c] = __float2bfloat16((v[j] - mean) * rstd * g[c] + bta[c]);
    }
}

// ---------------------------------------------------------------------------
// MFMA bf16 GEMM (round-4 best): BM=256, BN=128, BK=32, 8 waves in 4x2 grid,
// wave tile 64x64.  T4 counted-vmcnt pipeline: 3 LDS buffers, depth-2
// prefetch, vmcnt(3) at the barrier.  Used for qkv and proj only.
// MODE 0: +bias -> bf16 ; 2: +bias+scatter+resid -> f32
// ---------------------------------------------------------------------------
template <int MODE>
__global__ __launch_bounds__(512)
void gemm_kernel(const bf16* __restrict__ A, const bf16* __restrict__ BT,
                 const float* __restrict__ bias, void* __restrict__ out,
                 const float* __restrict__ resid, int M, int N, int K) {
    __shared__ bf16 As[3][8192];   // 3 x 16KB  [panel(0..3)][row(0..255)][8]
    __shared__ bf16 Bs[3][4096];   // 3 x  8KB  [panel(0..3)][row(0..127)][8]

    int tid = threadIdx.x;
    int wave = tid >> 6, lane = tid & 63, quad = lane >> 4, r = lane & 15;
    int wave_m = wave >> 1, wave_n = wave & 1;   // 4 x 2

    int nN = N >> 7;
    int nwg = gridDim.x;
    int bid = blockIdx.x;
    int q8 = nwg >> 3, r8 = nwg & 7;
    int xcd = bid & 7, loc = bid >> 3;
    int swz = (xcd < r8 ? xcd * (q8 + 1) : r8 * (q8 + 1) + (xcd - r8) * q8) + loc;
    int mtile = swz / nN;
    int ntile = swz - mtile * nN;
    int m0 = mtile << 8, n0 = ntile << 7;

    f32x4 acc[4][4] = {};

    auto stage = [&](int buf, int k0) {
        #pragma unroll
        for (int c = 0; c < 2; c++) {
            int ai = wave * 2 + c;                 // 0..15
            int slot = ai * 64 + lane;             // 0..1023 = panel*256 + row
            int panel = slot >> 8, row = slot & 255;
            gl_lds16(A + (size_t)(m0 + row) * K + k0 + panel * 8,
                     &As[buf][(ai * 64) * 8]);
        }
        {
            int slot = wave * 64 + lane;           // 0..511 = panel*128 + row
            int panel = slot >> 7, row = slot & 127;
            gl_lds16(BT + (size_t)(n0 + row) * K + k0 + panel * 8,
                     &Bs[buf][(wave * 64) * 8]);
        }
    };

    auto compute = [&](int buf) {
        short8 a[4], b[4];
        #pragma unroll
        for (int mt = 0; mt < 4; mt++)
            a[mt] = *(const short8*)&As[buf][(quad * 256 + wave_m * 64 + mt * 16 + r) * 8];
        #pragma unroll
        for (int nt = 0; nt < 4; nt++)
            b[nt] = *(const short8*)&Bs[buf][(quad * 128 + wave_n * 64 + nt * 16 + r) * 8];
        __builtin_amdgcn_s_setprio(1);
        #pragma unroll
        for (int mt = 0; mt < 4; mt++)
            #pragma unroll
            for (int nt = 0; nt < 4; nt++)
                acc[mt][nt] = __builtin_amdgcn_mfma_f32_16x16x32_bf16(
                    a[mt], b[nt], acc[mt][nt], 0, 0, 0);
        __builtin_amdgcn_s_setprio(0);
    };

    int nk = K >> 5;

    stage(0, 0);
    stage(1, 32);
    asm volatile("s_waitcnt vmcnt(3)" ::: "memory");
    __builtin_amdgcn_s_barrier();
    __builtin_amdgcn_sched_barrier(0);

    int buf = 0;
    for (int kt = 0; kt < nk; kt++) {
        int pf = kt + 2;
        int pbuf = buf + 2; if (pbuf >= 3) pbuf -= 3;
        if (pf < nk) stage(pbuf, pf << 5);
        compute(buf);
        if (kt + 1 < nk) {
            __builtin_amdgcn_sched_barrier(0);
            if (pf < nk) asm volatile("s_waitcnt vmcnt(3)" ::: "memory");
            else         asm volatile("s_waitcnt vmcnt(0)" ::: "memory");
            __builtin_amdgcn_s_barrier();
            __builtin_amdgcn_sched_barrier(0);
        }
        buf++; if (buf == 3) buf = 0;
    }

    #pragma unroll
    for (int mt = 0; mt < 4; mt++) {
        #pragma unroll
        for (int nt = 0; nt < 4; nt++) {
            int n = n0 + wave_n * 64 + nt * 16 + r;
            float bv = bias[n];
            #pragma unroll
            for (int reg = 0; reg < 4; reg++) {
                int m = m0 + wave_m * 64 + mt * 16 + quad * 4 + reg;
                float v = acc[mt][nt][reg] + bv;
                if (MODE == 0) {
                    ((bf16*)out)[(size_t)m * N + n] = __float2bfloat16(v);
                } else if (MODE == 2) {
                    int bw = m / 49, ntk = m - bw * 49;
                    int bb = bw >> 6, wi = bw & 63;
                    int wh = wi >> 3, wwi = wi & 7;
                    int rr = ntk / 7, cc = ntk - rr * 7;
                    int ho = wh * 7 + rr + SS; if (ho >= 56) ho -= 56;
                    int wo = wwi * 7 + cc + SS; if (wo >= 56) wo -= 56;
                    size_t dst = ((size_t)(bb * 3136 + ho * 56 + wo)) * C_DIM + n;
                    ((float*)out)[dst] = v + resid[dst];
                }
            }
        }
    }
}

// ---------------------------------------------------------------------------
// FUSED MLP v2: out = xmid + fc2(gelu(fc1(ln2out))).  One block = 64-token
// strip, 8 waves (512 thr).  Round-7 fixes:
//  * padded-LINEAR LDS (A rows 392 elem = 196 words == 4 mod 32; H rows 136
//    elem = 68 words == 4 mod 32) -> fragment reads tile all 32 banks
//    conflict-free; staging writes <=2-way (free).  No XOR anywhere.
//  * 8 waves: phase1 wave tile 64x16 (acc2[4]), phase2 64x48 (acc[4][3]).
//    LDS 50.2+17.4 = 67.6KB -> 2 blocks/CU = 16 waves/CU = 4/SIMD (2x TLP).
//  * raw s_barrier + lgkmcnt(0) only (NO vmcnt drain): in-flight W1/W2
//    register loads survive barriers; compiler waits at use point.
// h1 never touches HBM.  W1/W2 frags direct from global (L2-hot).
// ---------------------------------------------------------------------------
__global__ __launch_bounds__(512)
void fused_mlp_kernel(const bf16* __restrict__ A, const bf16* __restrict__ W1T,
                      const float* __restrict__ fb1, const bf16* __restrict__ W2T,
                      const float* __restrict__ fb2, const float* __restrict__ resid,
                      float* __restrict__ out) {
    __shared__ bf16 A_lds[64 * 392];   // 50176 B, padded rows
    __shared__ bf16 H_lds[64 * 136];   // 17408 B, padded rows

    int tid = threadIdx.x;
    int wave = tid >> 6, lane = tid & 63, quad = lane >> 4, r = lane & 15;
    int m0 = blockIdx.x * 64;

    // ---- stage A (linear, padded): 8 thr/token x 6 x 16B = 48 cols each ----
    {
        int token = tid >> 3, part = tid & 7;
        const bf16* src = A + (size_t)(m0 + token) * 384 + part * 48;
        #pragma unroll
        for (int j = 0; j < 6; j++) {
            short8 v = *(const short8*)(src + j * 8);
            *(short8*)&A_lds[token * 392 + part * 48 + j * 8] = v;
        }
    }
    asm volatile("s_waitcnt lgkmcnt(0)" ::: "memory");
    __builtin_amdgcn_s_barrier();
    __builtin_amdgcn_sched_barrier(0);

    f32x4 acc[4][3] = {};   // out acc: 64 tokens x 48 cols per wave

    for (int hc = 0; hc < 12; hc++) {
        // ---- phase 1: h[64 x 16 per wave] = A @ W1[:, hc*128 + wave*16 ..] ----
        f32x4 acc2[4] = {};
        #pragma unroll
        for (int ks = 0; ks < 12; ks++) {
            short8 a[4], b;
            #pragma unroll
            for (int mt = 0; mt < 4; mt++)
                a[mt] = *(const short8*)&A_lds[(mt * 16 + r) * 392 + ks * 32 + quad * 8];
            b = *(const short8*)(W1T + (size_t)(hc * 128 + wave * 16 + r) * 384 + ks * 32 + quad * 8);
            #pragma unroll
            for (int mt = 0; mt < 4; mt++)
                acc2[mt] = __builtin_amdgcn_mfma_f32_16x16x32_bf16(a[mt], b, acc2[mt], 0, 0, 0);
        }
        // bias + exact GELU -> H_lds (each wave owns its 16 cols)
        {
            int col = wave * 16 + r;
            float bv = fb1[hc * 128 + col];
            #pragma unroll
            for (int mt = 0; mt < 4; mt++) {
                #pragma unroll
                for (int reg = 0; reg < 4; reg++) {
                    int row = mt * 16 + quad * 4 + reg;
                    float v = acc2[mt][reg] + bv;
                    float gl = 0.5f * v * (1.0f + erff(v * 0.70710678118654752f));
                    H_lds[row * 136 + col] = __float2bfloat16(gl);
                }
            }
        }
        asm volatile("s_waitcnt lgkmcnt(0)" ::: "memory");   // H writes visible
        __builtin_amdgcn_s_barrier();                        // no vmcnt drain
        __builtin_amdgcn_sched_barrier(0);

        // ---- phase 2: acc += H @ W2[hc*128.., wave*48..] ----
        #pragma unroll
        for (int ks = 0; ks < 4; ks++) {
            short8 a2[4], b2[3];
            #pragma unroll
            for (int mt = 0; mt < 4; mt++)
                a2[mt] = *(const short8*)&H_lds[(mt * 16 + r) * 136 + ks * 32 + quad * 8];
            #pragma unroll
            for (int nt = 0; nt < 3; nt++)
                b2[nt] = *(const short8*)(W2T + (size_t)(wave * 48 + nt * 16 + r) * 1536
                                          + hc * 128 + ks * 32 + quad * 8);
            #pragma unroll
            for (int mt = 0; mt < 4; mt++)
                #pragma unroll
                for (int nt = 0; nt < 3; nt++)
                    acc[mt][nt] = __builtin_amdgcn_mfma_f32_16x16x32_bf16(
                        a2[mt], b2[nt], acc[mt][nt], 0, 0, 0);
        }
        // WAR barrier before next chunk's H writes (reads already consumed)
        __builtin_amdgcn_sched_barrier(0);
        __builtin_amdgcn_s_barrier();
        __builtin_amdgcn_sched_barrier(0);
    }

    // ---- epilogue: out = acc + fc2 bias + resid (f32) ----
    #pragma unroll
    for (int nt = 0; nt < 3; nt++) {
        int n = wave * 48 + nt * 16 + r;
        float bv = fb2[n];
        #pragma unroll
        for (int mt = 0; mt < 4; mt++) {
            #pragma unroll
            for (int reg = 0; reg < 4; reg++) {
                int m = m0 + mt * 16 + quad * 4 + reg;
                size_t idx = (size_t)m * 384 + n;
                out[idx] = acc[mt][nt][reg] + bv + resid[idx];
            }
        }
    }
}

// ---------------------------------------------------------------------------
// MFMA windowed attention.  Wave-per-(window,head); grid (1024, 3), 4 waves.
// ---------------------------------------------------------------------------
__global__ __launch_bounds__(256)
void attn_mfma_kernel(const bf16* __restrict__ qkv, const float* __restrict__ BM,
                      bf16* __restrict__ out) {
    __shared__ bf16 P_lds[4][4096];   // [wave][64*64] swizzled
    __shared__ bf16 V_lds[4][2048];   // [wave][32*64] swizzled (V^T)
    int wave = threadIdx.x >> 6, lane = threadIdx.x & 63;
    int quad = lane >> 4, m16 = lane & 15;
    int bw = blockIdx.x;
    int h = blockIdx.y * 4 + wave;
    int wi = bw & 63;

    const bf16* base = qkv + (size_t)bw * 49 * 1152 + h * 32;

    bf16* Vt = V_lds[wave];
    #pragma unroll
    for (int it = 0; it < 16; it++) {
        int idx = it * 64 + lane;          // n*16 + dpair
        int n = idx >> 4, dp = idx & 15;
        int d0 = dp * 2;
        unsigned val = 0;
        if (n < 49)
            val = *(const unsigned*)(base + (size_t)n * 1152 + 768 + d0);
        bf16 v0 = ((const bf16*)&val)[0], v1 = ((const bf16*)&val)[1];
        int cb = (n & 56);                  // chunk<<3
        Vt[d0 * 64 + ((cb ^ ((d0 & 7) << 3)) | (n & 7))] = v0;
        int d1 = d0 + 1;
        Vt[d1 * 64 + ((cb ^ ((d1 & 7) << 3)) | (n & 7))] = v1;
    }

    short8 qf[4], kf[4];
    #pragma unroll
    for (int t = 0; t < 4; t++) {
        int row = t * 16 + m16;
        int rc = (row < 49) ? row : 0;
        qf[t] = *(const short8*)(base + (size_t)rc * 1152 + quad * 8);
        kf[t] = *(const short8*)(base + (size_t)rc * 1152 + 384 + quad * 8);
    }
    f32x4 S[4][4] = {};
    #pragma unroll
    for (int mt = 0; mt < 4; mt++)
        #pragma unroll
        for (int nt = 0; nt < 4; nt++)
            S[mt][nt] = __builtin_amdgcn_mfma_f32_16x16x32_bf16(qf[mt], kf[nt], S[mt][nt], 0, 0, 0);

    const float* bmw = BM + (((size_t)wi * 12 + h) << 12);
    bf16* Pw = P_lds[wave];
    #pragma unroll
    for (int mt = 0; mt < 4; mt++) {
        #pragma unroll
        for (int reg = 0; reg < 4; reg++) {
            int row = mt * 16 + quad * 4 + reg;
            float p[4];
            float mx = -1e30f;
            #pragma unroll
            for (int nt = 0; nt < 4; nt++) {
                int col = nt * 16 + m16;
                float s = S[mt][nt][reg] * SCALE_ATTN + bmw[row * 64 + col];
                p[nt] = s;
                mx = fmaxf(mx, s);
            }
            #pragma unroll
            for (int o = 1; o < 16; o <<= 1) mx = fmaxf(mx, __shfl_xor(mx, o, 64));
            float sm = 0.f;
            #pragma unroll
            for (int nt = 0; nt < 4; nt++) { p[nt] = __expf(p[nt] - mx); sm += p[nt]; }
            #pragma unroll
            for (int o = 1; o < 16; o <<= 1) sm += __shfl_xor(sm, o, 64);
            float inv = 1.0f / sm;
            int r7 = (row & 7) << 3;
            #pragma unroll
            for (int nt = 0; nt < 4; nt++) {
                int col = nt * 16 + m16;
                int sw = ((col & 56) ^ r7) | (col & 7);
                Pw[row * 64 + sw] = __float2bfloat16(p[nt] * inv);
            }
        }
    }

    f32x4 O[4][2] = {};
    #pragma unroll
    for (int ks = 0; ks < 2; ks++) {
        int chunk = ks * 4 + quad;
        short8 pa[4], vb[2];
        #pragma unroll
        for (int mt = 0; mt < 4; mt++) {
            int row = mt * 16 + m16;
            pa[mt] = *(const short8*)&Pw[row * 64 + ((chunk ^ (row & 7)) << 3)];
        }
        #pragma unroll
        for (int nt = 0; nt < 2; nt++) {
            int d = nt * 16 + m16;
            vb[nt] = *(const short8*)&Vt[d * 64 + ((chunk ^ (d & 7)) << 3)];
        }
        #pragma unroll
        for (int mt = 0; mt < 4; mt++)
            #pragma unroll
            for (int nt = 0; nt < 2; nt++)
                O[mt][nt] = __builtin_amdgcn_mfma_f32_16x16x32_bf16(pa[mt], vb[nt], O[mt][nt], 0, 0, 0);
    }

    bf16* orow = out + (size_t)bw * 49 * 384 + h * 32;
    #pragma unroll
    for (int mt = 0; mt < 4; mt++) {
        #pragma unroll
        for (int reg = 0; reg < 4; reg++) {
            int row = mt * 16 + quad * 4 + reg;
            if (row < 49) {
                #pragma unroll
                for (int nt = 0; nt < 2; nt++)
                    orow[(size_t)row * 384 + nt * 16 + m16] = __float2bfloat16(O[mt][nt][reg]);
            }
        }
    }
}

// ---------------------------------------------------------------------------
extern "C" void kernel_launch(void* const* d_in, const int* in_sizes, int n_in,
                              void* d_out, int out_size, void* d_ws, size_t ws_size,
                              hipStream_t stream) {
    const float* x      = (const float*)d_in[0];
    const float* g1     = (const float*)d_in[1];
    const float* b1     = (const float*)d_in[2];
    const float* qkv_w  = (const float*)d_in[3];
    const float* qkv_b  = (const float*)d_in[4];
    const float* rpb    = (const float*)d_in[5];
    const float* proj_w = (const float*)d_in[6];
    const float* proj_b = (const float*)d_in[7];
    const float* g2     = (const float*)d_in[8];
    const float* b2     = (const float*)d_in[9];
    const float* fc1_w  = (const float*)d_in[10];
    const float* fc1_b  = (const float*)d_in[11];
    const float* fc2_w  = (const float*)d_in[12];
    const float* fc2_b  = (const float*)d_in[13];
    const int*   rel_idx   = (const int*)d_in[14];
    const float* attn_mask = (const float*)d_in[15];

    const int M = 50176;  // 16 * 56 * 56 tokens = 1024 windows * 49

    char* ws = (char*)d_ws;
    size_t off = 0;
    bf16* bufA   = (bf16*)(ws + off); off += (size_t)M * 384 * 2;    // win / attn_out / ln2out
    bf16* bufBC  = (bf16*)(ws + off); off += (size_t)M * 1536 * 2;   // qkv (1152 cols)
    float* xmid  = (float*)(ws + off); off += (size_t)M * 384 * 4;   // residual mid, fp32
    bf16* qkv_wT  = (bf16*)(ws + off); off += (size_t)1152 * 384 * 2;
    bf16* proj_wT = (bf16*)(ws + off); off += (size_t)384 * 384 * 2;
    bf16* fc1_wT  = (bf16*)(ws + off); off += (size_t)1536 * 384 * 2;
    bf16* fc2_wT  = (bf16*)(ws + off); off += (size_t)384 * 1536 * 2;
    // BM table lives in the unused tail of bufBC (qkv uses only 1152 of 1536 cols)
    float* BM = (float*)(bufBC + (size_t)M * 1152);   // 64*12*64*64 f32 = 12.6MB < 38.5MB free

    build_bm_kernel<<<64 * 12 * 4096 / 256, 256, 0, stream>>>(rpb, rel_idx, attn_mask, BM);

    transpose_cast_kernel<<<(384 * 1152 + 255) / 256, 256, 0, stream>>>(qkv_w, qkv_wT, 384, 1152);
    transpose_cast_kernel<<<(384 * 384 + 255) / 256, 256, 0, stream>>>(proj_w, proj_wT, 384, 384);
    transpose_cast_kernel<<<(384 * 1536 + 255) / 256, 256, 0, stream>>>(fc1_w, fc1_wT, 384, 1536);
    transpose_cast_kernel<<<(1536 * 384 + 255) / 256, 256, 0, stream>>>(fc2_w, fc2_wT, 1536, 384);

    // LN1 + shift + window partition -> bf16 win
    ln1_shift_window<<<M / 4, 256, 0, stream>>>(x, g1, b1, bufA);

    // qkv = win @ qkv_w + b  -> bf16
    gemm_kernel<0><<<(M / 256) * (1152 / 128), 512, 0, stream>>>(
        bufA, qkv_wT, qkv_b, bufBC, nullptr, M, 1152, 384);

    // windowed attention (MFMA) -> bufA (bf16)
    attn_mfma_kernel<<<dim3(1024, 3), 256, 0, stream>>>(bufBC, BM, bufA);

    // proj + window reverse + unshift + residual x -> xmid (fp32)
    gemm_kernel<2><<<(M / 256) * (384 / 128), 512, 0, stream>>>(
        bufA, proj_wT, proj_b, xmid, x, M, 384, 384);

    // LN2 -> bufA (bf16)
    ln2_kernel<<<M / 4, 256, 0, stream>>>(xmid, g2, b2, bufA);

    // fused MLP: d_out = xmid + fc2(gelu(fc1(bufA)))
    fused_mlp_kernel<<<M / 64, 512, 0, stream>>>(
        bufA, fc1_wT, fc1_b, fc2_wT, fc2_b, xmid, (float*)d_out);
}

// Round 11
// 714.465 us; speedup vs baseline: 1.1966x; 1.0033x over previous
//
#include <hip/hip_runtime.h>
#include <hip/hip_bf16.h>
#include <math.h>

typedef __hip_bfloat16 bf16;
typedef __attribute__((ext_vector_type(8))) short short8;
typedef __attribute__((ext_vector_type(4))) short s16x4;
typedef __attribute__((ext_vector_type(4))) float f32x4;

#define C_DIM 384
#define SS 3
#define SCALE_ATTN 0.17677669529663687f  // 32^-0.5
#define LN_EPS 1e-5f

typedef const __attribute__((address_space(1))) void g_cvoid;
typedef __attribute__((address_space(3))) void l_void;
__device__ __forceinline__ void gl_lds16(const void* g, void* l) {
    __builtin_amdgcn_global_load_lds((g_cvoid*)g, (l_void*)l, 16, 0, 0);
}

// ---------------------------------------------------------------------------
// Weight transpose + fp32->bf16 cast: in fp32 [R][Cc] -> out bf16 [Cc][R]
// ---------------------------------------------------------------------------
__global__ void transpose_cast_kernel(const float* __restrict__ in, bf16* __restrict__ out,
                                      int R, int Cc) {
    int idx = blockIdx.x * 256 + threadIdx.x;
    if (idx < R * Cc) {
        int r = idx / Cc, c = idx - r * Cc;
        out[(size_t)c * R + r] = __float2bfloat16(in[idx]);
    }
}

// ---------------------------------------------------------------------------
// Fused bias table: BM[wi][h][64][64] fp32, padded; cols>=49 (or rows>=49)
// get -1e30 so attention needs no separate masking.
// ---------------------------------------------------------------------------
__global__ void build_bm_kernel(const float* __restrict__ rpb, const int* __restrict__ rel_idx,
                                const float* __restrict__ mask, float* __restrict__ BM) {
    int idx = blockIdx.x * 256 + threadIdx.x;   // < 64*12*4096
    int col = idx & 63, row = (idx >> 6) & 63;
    int h = (idx >> 12) % 12, wi = idx / (12 * 4096);
    float v = -1e30f;
    if (row < 49 && col < 49)
        v = rpb[rel_idx[row * 49 + col] * 12 + h] + mask[(size_t)wi * 2401 + row * 49 + col];
    BM[idx] = v;
}

// ---------------------------------------------------------------------------
// LN1 + cyclic shift + window partition.  One wave per output token.
// ---------------------------------------------------------------------------
__global__ __launch_bounds__(256)
void ln1_shift_window(const float* __restrict__ x, const float* __restrict__ g,
                      const float* __restrict__ bta, bf16* __restrict__ win) {
    int wave = threadIdx.x >> 6, lane = threadIdx.x & 63;
    int token = blockIdx.x * 4 + wave;
    int bw = token / 49, ntk = token - bw * 49;
    int bb = bw >> 6, wi = bw & 63;
    int wh = wi >> 3, wwi = wi & 7;
    int rr = ntk / 7, cc = ntk - rr * 7;
    int hs = wh * 7 + rr + SS; if (hs >= 56) hs -= 56;
    int ws = wwi * 7 + cc + SS; if (ws >= 56) ws -= 56;
    const float* src = x + ((size_t)(bb * 3136 + hs * 56 + ws)) * C_DIM;

    float v[6]; float s = 0.f, sq = 0.f;
    #pragma unroll
    for (int j = 0; j < 6; j++) {
        v[j] = src[lane + j * 64];
        s += v[j]; sq += v[j] * v[j];
    }
    #pragma unroll
    for (int o = 32; o > 0; o >>= 1) { s += __shfl_xor(s, o, 64); sq += __shfl_xor(sq, o, 64); }
    float mean = s * (1.0f / 384.0f);
    float var  = sq * (1.0f / 384.0f) - mean * mean;
    float rstd = rsqrtf(var + LN_EPS);

    bf16* dst = win + (size_t)token * C_DIM;
    #pragma unroll
    for (int j = 0; j < 6; j++) {
        int c = lane + j * 64;
        dst[c] = __float2bfloat16((v[j] - mean) * rstd * g[c] + bta[c]);
    }
}

// ---------------------------------------------------------------------------
// LN2 over fp32 xmid -> bf16
// ---------------------------------------------------------------------------
__global__ __launch_bounds__(256)
void ln2_kernel(const float* __restrict__ xmid, const float* __restrict__ g,
                const float* __restrict__ bta, bf16* __restrict__ out) {
    int wave = threadIdx.x >> 6, lane = threadIdx.x & 63;
    int token = blockIdx.x * 4 + wave;
    const float* src = xmid + (size_t)token * C_DIM;
    float v[6]; float s = 0.f, sq = 0.f;
    #pragma unroll
    for (int j = 0; j < 6; j++) {
        v[j] = src[lane + j * 64];
        s += v[j]; sq += v[j] * v[j];
    }
    #pragma unroll
    for (int o = 32; o > 0; o >>= 1) { s += __shfl_xor(s, o, 64); sq += __shfl_xor(sq, o, 64); }
    float mean = s * (1.0f / 384.0f);
    float var  = sq * (1.0f / 384.0f) - mean * mean;
    float rstd = rsqrtf(var + LN_EPS);
    bf16* dst = out + (size_t)token * C_DIM;
    #pragma unroll
    for (int j = 0; j < 6; j++) {
        int c = lane + j * 64;
        dst[c] = __float2bfloat16((v[j] - mean) * rstd * g[c] + bta[c]);
    }
}

// ---------------------------------------------------------------------------
// MFMA bf16 GEMM (round-4 best): BM=256, BN=128, BK=32, 8 waves in 4x2 grid,
// wave tile 64x64.  T4 counted-vmcnt pipeline: 3 LDS buffers, depth-2
// prefetch, vmcnt(3) at the barrier.  Used for qkv and proj only.
// MODE 0: +bias -> bf16 ; 2: +bias+scatter+resid -> f32
// ---------------------------------------------------------------------------
template <int MODE>
__global__ __launch_bounds__(512)
void gemm_kernel(const bf16* __restrict__ A, const bf16* __restrict__ BT,
                 const float* __restrict__ bias, void* __restrict__ out,
                 const float* __restrict__ resid, int M, int N, int K) {
    __shared__ bf16 As[3][8192];   // 3 x 16KB  [panel(0..3)][row(0..255)][8]
    __shared__ bf16 Bs[3][4096];   // 3 x  8KB  [panel(0..3)][row(0..127)][8]

    int tid = threadIdx.x;
    int wave = tid >> 6, lane = tid & 63, quad = lane >> 4, r = lane & 15;
    int wave_m = wave >> 1, wave_n = wave & 1;   // 4 x 2

    int nN = N >> 7;
    int nwg = gridDim.x;
    int bid = blockIdx.x;
    int q8 = nwg >> 3, r8 = nwg & 7;
    int xcd = bid & 7, loc = bid >> 3;
    int swz = (xcd < r8 ? xcd * (q8 + 1) : r8 * (q8 + 1) + (xcd - r8) * q8) + loc;
    int mtile = swz / nN;
    int ntile = swz - mtile * nN;
    int m0 = mtile << 8, n0 = ntile << 7;

    f32x4 acc[4][4] = {};

    auto stage = [&](int buf, int k0) {
        #pragma unroll
        for (int c = 0; c < 2; c++) {
            int ai = wave * 2 + c;                 // 0..15
            int slot = ai * 64 + lane;             // 0..1023 = panel*256 + row
            int panel = slot >> 8, row = slot & 255;
            gl_lds16(A + (size_t)(m0 + row) * K + k0 + panel * 8,
                     &As[buf][(ai * 64) * 8]);
        }
        {
            int slot = wave * 64 + lane;           // 0..511 = panel*128 + row
            int panel = slot >> 7, row = slot & 127;
            gl_lds16(BT + (size_t)(n0 + row) * K + k0 + panel * 8,
                     &Bs[buf][(wave * 64) * 8]);
        }
    };

    auto compute = [&](int buf) {
        short8 a[4], b[4];
        #pragma unroll
        for (int mt = 0; mt < 4; mt++)
            a[mt] = *(const short8*)&As[buf][(quad * 256 + wave_m * 64 + mt * 16 + r) * 8];
        #pragma unroll
        for (int nt = 0; nt < 4; nt++)
            b[nt] = *(const short8*)&Bs[buf][(quad * 128 + wave_n * 64 + nt * 16 + r) * 8];
        __builtin_amdgcn_s_setprio(1);
        #pragma unroll
        for (int mt = 0; mt < 4; mt++)
            #pragma unroll
            for (int nt = 0; nt < 4; nt++)
                acc[mt][nt] = __builtin_amdgcn_mfma_f32_16x16x32_bf16(
                    a[mt], b[nt], acc[mt][nt], 0, 0, 0);
        __builtin_amdgcn_s_setprio(0);
    };

    int nk = K >> 5;

    stage(0, 0);
    stage(1, 32);
    asm volatile("s_waitcnt vmcnt(3)" ::: "memory");
    __builtin_amdgcn_s_barrier();
    __builtin_amdgcn_sched_barrier(0);

    int buf = 0;
    for (int kt = 0; kt < nk; kt++) {
        int pf = kt + 2;
        int pbuf = buf + 2; if (pbuf >= 3) pbuf -= 3;
        if (pf < nk) stage(pbuf, pf << 5);
        compute(buf);
        if (kt + 1 < nk) {
            __builtin_amdgcn_sched_barrier(0);
            if (pf < nk) asm volatile("s_waitcnt vmcnt(3)" ::: "memory");
            else         asm volatile("s_waitcnt vmcnt(0)" ::: "memory");
            __builtin_amdgcn_s_barrier();
            __builtin_amdgcn_sched_barrier(0);
        }
        buf++; if (buf == 3) buf = 0;
    }

    #pragma unroll
    for (int mt = 0; mt < 4; mt++) {
        #pragma unroll
        for (int nt = 0; nt < 4; nt++) {
            int n = n0 + wave_n * 64 + nt * 16 + r;
            float bv = bias[n];
            #pragma unroll
            for (int reg = 0; reg < 4; reg++) {
                int m = m0 + wave_m * 64 + mt * 16 + quad * 4 + reg;
                float v = acc[mt][nt][reg] + bv;
                if (MODE == 0) {
                    ((bf16*)out)[(size_t)m * N + n] = __float2bfloat16(v);
                } else if (MODE == 2) {
                    int bw = m / 49, ntk = m - bw * 49;
                    int bb = bw >> 6, wi = bw & 63;
                    int wh = wi >> 3, wwi = wi & 7;
                    int rr = ntk / 7, cc = ntk - rr * 7;
                    int ho = wh * 7 + rr + SS; if (ho >= 56) ho -= 56;
                    int wo = wwi * 7 + cc + SS; if (wo >= 56) wo -= 56;
                    size_t dst = ((size_t)(bb * 3136 + ho * 56 + wo)) * C_DIM + n;
                    ((float*)out)[dst] = v + resid[dst];
                }
            }
        }
    }
}

// ---------------------------------------------------------------------------
// FUSED MLP v3: out = xmid + fc2(gelu(fc1(ln2out))).  One block = 64-token
// strip, 8 waves (512 thr).  Round-8 fix: phase-1 computes h^T via SWAPPED
// operands mfma(W1_frag, A_frag) so each lane's 4 C/D regs are 4 CONSECUTIVE
// hidden indices of ONE token -> packed ds_write_b64 into row-major H
// (replaces 16 scalar stores/chunk whose 4-way word-bank aliasing produced
// the measured 19.6M SQ_LDS_BANK_CONFLICT).  Write pattern word = tok*68 +
// wave*8 + quad*2 is uniform at the 4-words/bank floor.
// LDS: A rows padded to 392 elem (196w == 4 mod 32), H rows 136 elem
// (68w == 4 mod 32) -> all b128 fragment reads at the 8-cycle floor.
// 8 waves: phase1 wave tile 16 hidden x 64 tokens (acc2[4 token-tiles]);
// phase2 64 tokens x 48 out-cols (acc[4][3]).  LDS 67.6KB -> 2 blocks/CU.
// raw s_barrier + lgkmcnt(0) only (no vmcnt drain): W1/W2 register loads
// survive barriers.  h1 never touches HBM.
// ---------------------------------------------------------------------------
__global__ __launch_bounds__(512)
void fused_mlp_kernel(const bf16* __restrict__ A, const bf16* __restrict__ W1T,
                      const float* __restrict__ fb1, const bf16* __restrict__ W2T,
                      const float* __restrict__ fb2, const float* __restrict__ resid,
                      float* __restrict__ out) {
    __shared__ bf16 A_lds[64 * 392];   // 50176 B, padded rows
    __shared__ bf16 H_lds[64 * 136];   // 17408 B, padded rows

    int tid = threadIdx.x;
    int wave = tid >> 6, lane = tid & 63, quad = lane >> 4, r = lane & 15;
    int m0 = blockIdx.x * 64;

    // ---- stage A (linear, padded): 8 thr/token x 6 x 16B = 48 cols each ----
    {
        int token = tid >> 3, part = tid & 7;
        const bf16* src = A + (size_t)(m0 + token) * 384 + part * 48;
        #pragma unroll
        for (int j = 0; j < 6; j++) {
            short8 v = *(const short8*)(src + j * 8);
            *(short8*)&A_lds[token * 392 + part * 48 + j * 8] = v;
        }
    }
    asm volatile("s_waitcnt lgkmcnt(0)" ::: "memory");
    __builtin_amdgcn_s_barrier();
    __builtin_amdgcn_sched_barrier(0);

    f32x4 acc[4][3] = {};   // out acc: 64 tokens x 48 cols per wave

    for (int hc = 0; hc < 12; hc++) {
        // ---- phase 1 (swapped): hT[16 hid x 64 tok] = W1_frag x A_frag ----
        // acc2[tt]: lane(quad,r) holds hidden rows wave*16+quad*4+0..3,
        // token col tt*16 + r.
        f32x4 acc2[4] = {};
        #pragma unroll
        for (int ks = 0; ks < 12; ks++) {
            short8 w1, a[4];
            w1 = *(const short8*)(W1T + (size_t)(hc * 128 + wave * 16 + r) * 384 + ks * 32 + quad * 8);
            #pragma unroll
            for (int tt = 0; tt < 4; tt++)
                a[tt] = *(const short8*)&A_lds[(tt * 16 + r) * 392 + ks * 32 + quad * 8];
            #pragma unroll
            for (int tt = 0; tt < 4; tt++)
                acc2[tt] = __builtin_amdgcn_mfma_f32_16x16x32_bf16(w1, a[tt], acc2[tt], 0, 0, 0);
        }
        // bias + exact GELU -> packed b64 store: 4 consecutive hidden of one token
        {
            int hb = wave * 16 + quad * 4;     // hidden base (4 consecutive)
            float b0 = fb1[hc * 128 + hb + 0], b1 = fb1[hc * 128 + hb + 1];
            float b2 = fb1[hc * 128 + hb + 2], b3 = fb1[hc * 128 + hb + 3];
            #pragma unroll
            for (int tt = 0; tt < 4; tt++) {
                int token = tt * 16 + r;
                float v0 = acc2[tt][0] + b0, v1 = acc2[tt][1] + b1;
                float v2 = acc2[tt][2] + b2, v3 = acc2[tt][3] + b3;
                v0 = 0.5f * v0 * (1.0f + erff(v0 * 0.70710678118654752f));
                v1 = 0.5f * v1 * (1.0f + erff(v1 * 0.70710678118654752f));
                v2 = 0.5f * v2 * (1.0f + erff(v2 * 0.70710678118654752f));
                v3 = 0.5f * v3 * (1.0f + erff(v3 * 0.70710678118654752f));
                s16x4 pk;
                pk[0] = (short)__bfloat16_as_ushort(__float2bfloat16(v0));
                pk[1] = (short)__bfloat16_as_ushort(__float2bfloat16(v1));
                pk[2] = (short)__bfloat16_as_ushort(__float2bfloat16(v2));
                pk[3] = (short)__bfloat16_as_ushort(__float2bfloat16(v3));
                *(s16x4*)&H_lds[token * 136 + hb] = pk;
            }
        }
        asm volatile("s_waitcnt lgkmcnt(0)" ::: "memory");   // H writes visible
        __builtin_amdgcn_s_barrier();                        // no vmcnt drain
        __builtin_amdgcn_sched_barrier(0);

        // ---- phase 2: acc += H @ W2[hc*128.., wave*48..] ----
        #pragma unroll
        for (int ks = 0; ks < 4; ks++) {
            short8 a2[4], b2[3];
            #pragma unroll
            for (int mt = 0; mt < 4; mt++)
                a2[mt] = *(const short8*)&H_lds[(mt * 16 + r) * 136 + ks * 32 + quad * 8];
            #pragma unroll
            for (int nt = 0; nt < 3; nt++)
                b2[nt] = *(const short8*)(W2T + (size_t)(wave * 48 + nt * 16 + r) * 1536
                                          + hc * 128 + ks * 32 + quad * 8);
            #pragma unroll
            for (int mt = 0; mt < 4; mt++)
                #pragma unroll
                for (int nt = 0; nt < 3; nt++)
                    acc[mt][nt] = __builtin_amdgcn_mfma_f32_16x16x32_bf16(
                        a2[mt], b2[nt], acc[mt][nt], 0, 0, 0);
        }
        // WAR barrier before next chunk's H writes (reads already consumed)
        __builtin_amdgcn_sched_barrier(0);
        __builtin_amdgcn_s_barrier();
        __builtin_amdgcn_sched_barrier(0);
    }

    // ---- epilogue: out = acc + fc2 bias + resid (f32) ----
    #pragma unroll
    for (int nt = 0; nt < 3; nt++) {
        int n = wave * 48 + nt * 16 + r;
        float bv = fb2[n];
        #pragma unroll
        for (int mt = 0; mt < 4; mt++) {
            #pragma unroll
            for (int reg = 0; reg < 4; reg++) {
                int m = m0 + mt * 16 + quad * 4 + reg;
                size_t idx = (size_t)m * 384 + n;
                out[idx] = acc[mt][nt][reg] + bv + resid[idx];
            }
        }
    }
}

// ---------------------------------------------------------------------------
// MFMA windowed attention.  Wave-per-(window,head); grid (1024, 3), 4 waves.
// ---------------------------------------------------------------------------
__global__ __launch_bounds__(256)
void attn_mfma_kernel(const bf16* __restrict__ qkv, const float* __restrict__ BM,
                      bf16* __restrict__ out) {
    __shared__ bf16 P_lds[4][4096];   // [wave][64*64] swizzled
    __shared__ bf16 V_lds[4][2048];   // [wave][32*64] swizzled (V^T)
    int wave = threadIdx.x >> 6, lane = threadIdx.x & 63;
    int quad = lane >> 4, m16 = lane & 15;
    int bw = blockIdx.x;
    int h = blockIdx.y * 4 + wave;
    int wi = bw & 63;

    const bf16* base = qkv + (size_t)bw * 49 * 1152 + h * 32;

    bf16* Vt = V_lds[wave];
    #pragma unroll
    for (int it = 0; it < 16; it++) {
        int idx = it * 64 + lane;          // n*16 + dpair
        int n = idx >> 4, dp = idx & 15;
        int d0 = dp * 2;
        unsigned val = 0;
        if (n < 49)
            val = *(const unsigned*)(base + (size_t)n * 1152 + 768 + d0);
        bf16 v0 = ((const bf16*)&val)[0], v1 = ((const bf16*)&val)[1];
        int cb = (n & 56);                  // chunk<<3
        Vt[d0 * 64 + ((cb ^ ((d0 & 7) << 3)) | (n & 7))] = v0;
        int d1 = d0 + 1;
        Vt[d1 * 64 + ((cb ^ ((d1 & 7) << 3)) | (n & 7))] = v1;
    }

    short8 qf[4], kf[4];
    #pragma unroll
    for (int t = 0; t < 4; t++) {
        int row = t * 16 + m16;
        int rc = (row < 49) ? row : 0;
        qf[t] = *(const short8*)(base + (size_t)rc * 1152 + quad * 8);
        kf[t] = *(const short8*)(base + (size_t)rc * 1152 + 384 + quad * 8);
    }
    f32x4 S[4][4] = {};
    #pragma unroll
    for (int mt = 0; mt < 4; mt++)
        #pragma unroll
        for (int nt = 0; nt < 4; nt++)
            S[mt][nt] = __builtin_amdgcn_mfma_f32_16x16x32_bf16(qf[mt], kf[nt], S[mt][nt], 0, 0, 0);

    const float* bmw = BM + (((size_t)wi * 12 + h) << 12);
    bf16* Pw = P_lds[wave];
    #pragma unroll
    for (int mt = 0; mt < 4; mt++) {
        #pragma unroll
        for (int reg = 0; reg < 4; reg++) {
            int row = mt * 16 + quad * 4 + reg;
            float p[4];
            float mx = -1e30f;
            #pragma unroll
            for (int nt = 0; nt < 4; nt++) {
                int col = nt * 16 + m16;
                float s = S[mt][nt][reg] * SCALE_ATTN + bmw[row * 64 + col];
                p[nt] = s;
                mx = fmaxf(mx, s);
            }
            #pragma unroll
            for (int o = 1; o < 16; o <<= 1) mx = fmaxf(mx, __shfl_xor(mx, o, 64));
            float sm = 0.f;
            #pragma unroll
            for (int nt = 0; nt < 4; nt++) { p[nt] = __expf(p[nt] - mx); sm += p[nt]; }
            #pragma unroll
            for (int o = 1; o < 16; o <<= 1) sm += __shfl_xor(sm, o, 64);
            float inv = 1.0f / sm;
            int r7 = (row & 7) << 3;
            #pragma unroll
            for (int nt = 0; nt < 4; nt++) {
                int col = nt * 16 + m16;
                int sw = ((col & 56) ^ r7) | (col & 7);
                Pw[row * 64 + sw] = __float2bfloat16(p[nt] * inv);
            }
        }
    }

    f32x4 O[4][2] = {};
    #pragma unroll
    for (int ks = 0; ks < 2; ks++) {
        int chunk = ks * 4 + quad;
        short8 pa[4], vb[2];
        #pragma unroll
        for (int mt = 0; mt < 4; mt++) {
            int row = mt * 16 + m16;
            pa[mt] = *(const short8*)&Pw[row * 64 + ((chunk ^ (row & 7)) << 3)];
        }
        #pragma unroll
        for (int nt = 0; nt < 2; nt++) {
            int d = nt * 16 + m16;
            vb[nt] = *(const short8*)&Vt[d * 64 + ((chunk ^ (d & 7)) << 3)];
        }
        #pragma unroll
        for (int mt = 0; mt < 4; mt++)
            #pragma unroll
            for (int nt = 0; nt < 2; nt++)
                O[mt][nt] = __builtin_amdgcn_mfma_f32_16x16x32_bf16(pa[mt], vb[nt], O[mt][nt], 0, 0, 0);
    }

    bf16* orow = out + (size_t)bw * 49 * 384 + h * 32;
    #pragma unroll
    for (int mt = 0; mt < 4; mt++) {
        #pragma unroll
        for (int reg = 0; reg < 4; reg++) {
            int row = mt * 16 + quad * 4 + reg;
            if (row < 49) {
                #pragma unroll
                for (int nt = 0; nt < 2; nt++)
                    orow[(size_t)row * 384 + nt * 16 + m16] = __float2bfloat16(O[mt][nt][reg]);
            }
        }
    }
}

// ---------------------------------------------------------------------------
extern "C" void kernel_launch(void* const* d_in, const int* in_sizes, int n_in,
                              void* d_out, int out_size, void* d_ws, size_t ws_size,
                              hipStream_t stream) {
    const float* x      = (const float*)d_in[0];
    const float* g1     = (const float*)d_in[1];
    const float* b1     = (const float*)d_in[2];
    const float* qkv_w  = (const float*)d_in[3];
    const float* qkv_b  = (const float*)d_in[4];
    const float* rpb    = (const float*)d_in[5];
    const float* proj_w = (const float*)d_in[6];
    const float* proj_b = (const float*)d_in[7];
    const float* g2     = (const float*)d_in[8];
    const float* b2     = (const float*)d_in[9];
    const float* fc1_w  = (const float*)d_in[10];
    const float* fc1_b  = (const float*)d_in[11];
    const float* fc2_w  = (const float*)d_in[12];
    const float* fc2_b  = (const float*)d_in[13];
    const int*   rel_idx   = (const int*)d_in[14];
    const float* attn_mask = (const float*)d_in[15];

    const int M = 50176;  // 16 * 56 * 56 tokens = 1024 windows * 49

    char* ws = (char*)d_ws;
    size_t off = 0;
    bf16* bufA   = (bf16*)(ws + off); off += (size_t)M * 384 * 2;    // win / attn_out / ln2out
    bf16* bufBC  = (bf16*)(ws + off); off += (size_t)M * 1536 * 2;   // qkv (1152 cols)
    float* xmid  = (float*)(ws + off); off += (size_t)M * 384 * 4;   // residual mid, fp32
    bf16* qkv_wT  = (bf16*)(ws + off); off += (size_t)1152 * 384 * 2;
    bf16* proj_wT = (bf16*)(ws + off); off += (size_t)384 * 384 * 2;
    bf16* fc1_wT  = (bf16*)(ws + off); off += (size_t)1536 * 384 * 2;
    bf16* fc2_wT  = (bf16*)(ws + off); off += (size_t)384 * 1536 * 2;
    // BM table lives in the unused tail of bufBC (qkv uses only 1152 of 1536 cols)
    float* BM = (float*)(bufBC + (size_t)M * 1152);   // 64*12*64*64 f32 = 12.6MB < 38.5MB free

    build_bm_kernel<<<64 * 12 * 4096 / 256, 256, 0, stream>>>(rpb, rel_idx, attn_mask, BM);

    transpose_cast_kernel<<<(384 * 1152 + 255) / 256, 256, 0, stream>>>(qkv_w, qkv_wT, 384, 1152);
    transpose_cast_kernel<<<(384 * 384 + 255) / 256, 256, 0, stream>>>(proj_w, proj_wT, 384, 384);
    transpose_cast_kernel<<<(384 * 1536 + 255) / 256, 256, 0, stream>>>(fc1_w, fc1_wT, 384, 1536);
    transpose_cast_kernel<<<(1536 * 384 + 255) / 256, 256, 0, stream>>>(fc2_w, fc2_wT, 1536, 384);

    // LN1 + shift + window partition -> bf16 win
    ln1_shift_window<<<M / 4, 256, 0, stream>>>(x, g1, b1, bufA);

    // qkv = win @ qkv_w + b  -> bf16
    gemm_kernel<0><<<(M / 256) * (1152 / 128), 512, 0, stream>>>(
        bufA, qkv_wT, qkv_b, bufBC, nullptr, M, 1152, 384);

    // windowed attention (MFMA) -> bufA (bf16)
    attn_mfma_kernel<<<dim3(1024, 3), 256, 0, stream>>>(bufBC, BM, bufA);

    // proj + window reverse + unshift + residual x -> xmid (fp32)
    gemm_kernel<2><<<(M / 256) * (384 / 128), 512, 0, stream>>>(
        bufA, proj_wT, proj_b, xmid, x, M, 384, 384);

    // LN2 -> bufA (bf16)
    ln2_kernel<<<M / 4, 256, 0, stream>>>(xmid, g2, b2, bufA);

    // fused MLP: d_out = xmid + fc2(gelu(fc1(bufA)))
    fused_mlp_kernel<<<M / 64, 512, 0, stream>>>(
        bufA, fc1_wT, fc1_b, fc2_wT, fc2_b, xmid, (float*)d_out);
}